// Round 2
// baseline (1621.715 us; speedup 1.0000x reference)
//
#include <hip/hip_runtime.h>
#include <math.h>

#define NN 30000
#define NE 480000
#define TPB 256

// workspace layout (float offsets): Z [0,30000); Q [30000,630000); EVAL [630000,1110000)
#define Q_OFF  30000
#define EV_OFF 630000

#define INV_SQRT2  0.70710678118654752f
#define INV_SQRT8  0.35355339059327376f
#define INV_SQRT24 0.20412414523193150f
#define TP_FOLD    0.08838834764831845f   // (1/8 radial) * (1/sqrt2)
#define D0S        0.08838834764831845f   // (1/MUL0_OUT=8) * (1/sqrt2)
#define D1S        0.10206207261596575f   // 1/(sqrt3*4) * (1/sqrt2)

// ---------- per-node q0 (8) and q1 (4x3), raw per reference ----------
__global__ __launch_bounds__(TPB) void prep_q(
    const float* __restrict__ x,
    const float* __restrict__ wq0, const float* __restrict__ wq1,
    float* __restrict__ q)
{
    int n = blockIdx.x * TPB + threadIdx.x;
    if (n >= NN) return;
    const float* xr = x + (size_t)n * 40;
    float* o = q + (size_t)n * 20;
#pragma unroll
    for (int b = 0; b < 8; ++b) {
        float acc = 0.f;
#pragma unroll
        for (int a = 0; a < 16; ++a) acc += xr[a] * wq0[a * 8 + b];
        o[b] = acc * 0.25f;                       // / sqrt(MUL0_IN=16)
    }
#pragma unroll
    for (int b = 0; b < 4; ++b)
#pragma unroll
        for (int c = 0; c < 3; ++c) {
            float acc = 0.f;
#pragma unroll
            for (int a = 0; a < 8; ++a) acc += xr[16 + a * 3 + c] * wq1[a * 4 + b];
            o[8 + b * 3 + c] = acc * INV_SQRT8;   // / sqrt(MUL1_IN=8)
        }
}

// ---------- per-edge pass; ISV=false: scores+Z, ISV=true: weighted scatter ----------
template <bool ISV>
__global__ __launch_bounds__(TPB) void edge_pass(
    const float* __restrict__ x, const int* __restrict__ ei,
    const float* __restrict__ ea, const float* __restrict__ emb,
    const float* __restrict__ el,
    const float* __restrict__ w1, const float* __restrict__ w2,
    const float* __restrict__ wd0, const float* __restrict__ wd1,
    const float* __restrict__ qn,
    float* __restrict__ evals, float* __restrict__ Z,
    float* __restrict__ out)
{
    const int e = blockIdx.x * TPB + threadIdx.x;   // NE % TPB == 0
    const int i = ei[e];
    const int j = ei[NE + e];

    const float y0  = ea[(size_t)e * 4 + 0];
    const float y1x = ea[(size_t)e * 4 + 1];
    const float y1y = ea[(size_t)e * 4 + 2];
    const float y1z = ea[(size_t)e * 4 + 3];

    // hidden layer h = silu(emb @ W1 / 4), literal
    float h[64];
    {
        float em[16];
#pragma unroll
        for (int a = 0; a < 16; ++a) em[a] = emb[(size_t)e * 16 + a];
#pragma unroll
        for (int hh = 0; hh < 64; ++hh) {
            float acc = 0.f;
#pragma unroll
            for (int a = 0; a < 16; ++a) acc += em[a] * w1[a * 64 + hh];
            acc *= 0.25f;                          // / sqrt(NB=16)
            h[hh] = acc / (1.f + expf(-acc));      // silu
        }
    }

    const float* xi = x + (size_t)i * 40;

    float ss[8], uu[8], su[4], us[12];
#pragma unroll
    for (int b = 0; b < 8; ++b) { ss[b] = 0.f; uu[b] = 0.f; }
#pragma unroll
    for (int b = 0; b < 4; ++b) su[b] = 0.f;
#pragma unroll
    for (int b = 0; b < 12; ++b) us[b] = 0.f;

    // a in [0,16): ss block (m = a*8+b) and su block (m = 192 + a*4+b)
#pragma unroll 1
    for (int a = 0; a < 16; ++a) {
        float w8[8] = {0.f,0.f,0.f,0.f,0.f,0.f,0.f,0.f};
        float w4[4] = {0.f,0.f,0.f,0.f};
        const float* wss = w2 + a * 8;
        const float* wsu = w2 + 192 + a * 4;
#pragma unroll
        for (int hh = 0; hh < 64; ++hh) {
            const float hv = h[hh];
            const int r = hh * 288;
#pragma unroll
            for (int b = 0; b < 8; ++b) w8[b] += hv * wss[r + b];
#pragma unroll
            for (int b = 0; b < 4; ++b) w4[b] += hv * wsu[r + b];
        }
        const float xv = xi[a];
#pragma unroll
        for (int b = 0; b < 8; ++b) ss[b] += xv * w8[b];
#pragma unroll
        for (int b = 0; b < 4; ++b) su[b] += xv * w4[b];
    }

    // a in [0,8): uu block (m = 128 + a*8+b) and us block (m = 256 + a*4+b)
#pragma unroll 1
    for (int a = 0; a < 8; ++a) {
        float w8[8] = {0.f,0.f,0.f,0.f,0.f,0.f,0.f,0.f};
        float w4[4] = {0.f,0.f,0.f,0.f};
        const float* wuu = w2 + 128 + a * 8;
        const float* wus = w2 + 256 + a * 4;
#pragma unroll
        for (int hh = 0; hh < 64; ++hh) {
            const float hv = h[hh];
            const int r = hh * 288;
#pragma unroll
            for (int b = 0; b < 8; ++b) w8[b] += hv * wuu[r + b];
#pragma unroll
            for (int b = 0; b < 4; ++b) w4[b] += hv * wus[r + b];
        }
        const float u0 = xi[16 + a * 3 + 0];
        const float u1 = xi[16 + a * 3 + 1];
        const float u2 = xi[16 + a * 3 + 2];
        const float xy = u0 * y1x + u1 * y1y + u2 * y1z;
#pragma unroll
        for (int b = 0; b < 8; ++b) uu[b] += xy * w8[b];
#pragma unroll
        for (int b = 0; b < 4; ++b) {
            us[b * 3 + 0] += u0 * w4[b];
            us[b * 3 + 1] += u1 * w4[b];
            us[b * 3 + 2] += u2 * w4[b];
        }
    }

    // apply reference normalizations:
    // out0 = (ss*y0/4 + uu/sqrt24)/sqrt2, radial carries extra /8  (TP_FOLD = 1/(8*sqrt2))
    // out1 = (su*y1/4 + us*y0/sqrt8)/sqrt2, same radial /8
    float k0[8], k1[12];
#pragma unroll
    for (int b = 0; b < 8; ++b)
        k0[b] = (ss[b] * y0 * 0.25f + uu[b] * INV_SQRT24) * TP_FOLD;
#pragma unroll
    for (int b = 0; b < 4; ++b) {
        k1[b * 3 + 0] = (su[b] * 0.25f * y1x + us[b * 3 + 0] * INV_SQRT8 * y0) * TP_FOLD;
        k1[b * 3 + 1] = (su[b] * 0.25f * y1y + us[b * 3 + 1] * INV_SQRT8 * y0) * TP_FOLD;
        k1[b * 3 + 2] = (su[b] * 0.25f * y1z + us[b * 3 + 2] * INV_SQRT8 * y0) * TP_FOLD;
    }

    if constexpr (!ISV) {
        const float* qj = qn + (size_t)j * 20;
        float d0 = 0.f;
#pragma unroll
        for (int a = 0; a < 8; ++a) {
            float t = 0.f;
#pragma unroll
            for (int b = 0; b < 8; ++b) t += k0[b] * wd0[a * 8 + b];
            d0 += qj[a] * t;
        }
        float d1 = 0.f;
#pragma unroll
        for (int a = 0; a < 4; ++a)
#pragma unroll
            for (int c = 0; c < 3; ++c) {
                float t = 0.f;
#pragma unroll
                for (int b = 0; b < 4; ++b) t += k1[b * 3 + c] * wd1[a * 4 + b];
                d1 += qj[8 + a * 3 + c] * t;
            }
        const float d = d0 * D0S + d1 * D1S;
        const float len = el[e];
        const float tt = 10.f * (1.f - len / 3.15f);
        float cut = 0.f;
        if (tt > 0.f) cut = expf(-1.f / fmaxf(tt, 1e-6f));
        const float ev = cut * expf(d);
        evals[e] = ev;
        atomicAdd(Z + j, ev);
    } else {
        const float ev = evals[e];
        const float zz = Z[j];
        const float wgt = sqrtf(fmaxf(ev / zz, 0.f));
        float* o = out + (size_t)j * 20;
#pragma unroll
        for (int b = 0; b < 8; ++b) atomicAdd(o + b, wgt * k0[b]);
#pragma unroll
        for (int t = 0; t < 12; ++t) atomicAdd(o + 8 + t, wgt * k1[t]);
    }
}

extern "C" void kernel_launch(void* const* d_in, const int* in_sizes, int n_in,
                              void* d_out, int out_size, void* d_ws, size_t ws_size,
                              hipStream_t stream)
{
    const float* x     = (const float*)d_in[0];
    const int*   eidx  = (const int*)d_in[1];
    const float* eattr = (const float*)d_in[2];
    const float* emb   = (const float*)d_in[3];
    const float* elen  = (const float*)d_in[4];
    const float* wq0   = (const float*)d_in[5];
    const float* wq1   = (const float*)d_in[6];
    const float* wk1   = (const float*)d_in[7];
    const float* wk2   = (const float*)d_in[8];
    const float* wv1   = (const float*)d_in[9];
    const float* wv2   = (const float*)d_in[10];
    const float* wd0   = (const float*)d_in[11];
    const float* wd1   = (const float*)d_in[12];

    float* ws  = (float*)d_ws;
    float* out = (float*)d_out;

    hipMemsetAsync(ws, 0, NN * sizeof(float), stream);                 // Z
    hipMemsetAsync(out, 0, (size_t)out_size * sizeof(float), stream);

    prep_q<<<(NN + TPB - 1) / TPB, TPB, 0, stream>>>(x, wq0, wq1, ws + Q_OFF);

    edge_pass<false><<<NE / TPB, TPB, 0, stream>>>(
        x, eidx, eattr, emb, elen, wk1, wk2, wd0, wd1,
        ws + Q_OFF, ws + EV_OFF, ws, out);
    edge_pass<true><<<NE / TPB, TPB, 0, stream>>>(
        x, eidx, eattr, emb, elen, wv1, wv2, wd0, wd1,
        ws + Q_OFF, ws + EV_OFF, ws, out);
}

// Round 3
// 924.046 us; speedup vs baseline: 1.7550x; 1.7550x over previous
//
#include <hip/hip_runtime.h>
#include <math.h>

#define NN 30000
#define NE 480000
#define TPB 256

// workspace layout (float/dword offsets)
#define Q_OFF    30000
#define EV_OFF   630000
#define WK1P_OFF 1110000   // 512 dwords (half2 pairs over a)
#define WV1P_OFF 1110512
#define WK2P_OFF 1111024   // 9216 dwords (half2 pairs over hh)
#define WV2P_OFF 1120240
// total 1129456 floats (~4.52 MB)

#define INV_SQRT8  0.35355339059327376f
#define INV_SQRT24 0.20412414523193150f
#define TP_FOLD    0.08838834764831845f   // (1/8 radial) * (1/sqrt2)
#define D0S        0.08838834764831845f   // (1/8) * (1/sqrt2)
#define D1S        0.10206207261596575f   // 1/(sqrt3*4*sqrt2)

typedef _Float16 half2v __attribute__((ext_vector_type(2)));

__device__ __forceinline__ float fdot2(half2v a, half2v b, float c) {
#if __has_builtin(__builtin_amdgcn_fdot2)
    return __builtin_amdgcn_fdot2(a, b, c, false);
#else
    return c + (float)a.x * (float)b.x + (float)a.y * (float)b.y;
#endif
}

// ---------- pack weights to fp16 pairs ----------
// w1p[hh*8+a2] = (w1[2a2][hh], w1[2a2+1][hh]) * 0.25    (fold /sqrt(NB))
// w2p[m*32+hh2] = (w2[2hh2][m], w2[2hh2+1][m])           (raw; scales applied at end)
__global__ __launch_bounds__(TPB) void prep_pack(
    const float* __restrict__ wk1, const float* __restrict__ wk2,
    const float* __restrict__ wv1, const float* __restrict__ wv2,
    half2v* __restrict__ wk1p, half2v* __restrict__ wv1p,
    half2v* __restrict__ wk2p, half2v* __restrict__ wv2p)
{
    int t = blockIdx.x * TPB + threadIdx.x;   // 9216 threads exactly
    int m = t >> 5, hh2 = t & 31;
    wk2p[t] = half2v{(_Float16)wk2[(2 * hh2) * 288 + m],
                     (_Float16)wk2[(2 * hh2 + 1) * 288 + m]};
    wv2p[t] = half2v{(_Float16)wv2[(2 * hh2) * 288 + m],
                     (_Float16)wv2[(2 * hh2 + 1) * 288 + m]};
    if (t < 512) {
        int hh = t >> 3, a2 = t & 7;
        wk1p[t] = half2v{(_Float16)(wk1[(2 * a2) * 64 + hh] * 0.25f),
                         (_Float16)(wk1[(2 * a2 + 1) * 64 + hh] * 0.25f)};
        wv1p[t] = half2v{(_Float16)(wv1[(2 * a2) * 64 + hh] * 0.25f),
                         (_Float16)(wv1[(2 * a2 + 1) * 64 + hh] * 0.25f)};
    }
}

// ---------- per-node q0 (8) and q1 (4x3) ----------
__global__ __launch_bounds__(TPB) void prep_q(
    const float* __restrict__ x,
    const float* __restrict__ wq0, const float* __restrict__ wq1,
    float* __restrict__ q)
{
    int n = blockIdx.x * TPB + threadIdx.x;
    if (n >= NN) return;
    const float* xr = x + (size_t)n * 40;
    float* o = q + (size_t)n * 20;
#pragma unroll
    for (int b = 0; b < 8; ++b) {
        float acc = 0.f;
#pragma unroll
        for (int a = 0; a < 16; ++a) acc += xr[a] * wq0[a * 8 + b];
        o[b] = acc * 0.25f;
    }
#pragma unroll
    for (int b = 0; b < 4; ++b)
#pragma unroll
        for (int c = 0; c < 3; ++c) {
            float acc = 0.f;
#pragma unroll
            for (int a = 0; a < 8; ++a) acc += xr[16 + a * 3 + c] * wq1[a * 4 + b];
            o[8 + b * 3 + c] = acc * INV_SQRT8;
        }
}

// ---------- per-edge pass; ISV=false: scores+Z, ISV=true: weighted scatter ----------
template <bool ISV>
__global__ __launch_bounds__(TPB, 4) void edge_pass(
    const float* __restrict__ x, const int* __restrict__ ei,
    const float* __restrict__ ea, const float* __restrict__ emb,
    const float* __restrict__ el,
    const half2v* __restrict__ w1p, const half2v* __restrict__ w2p,
    const float* __restrict__ wd0, const float* __restrict__ wd1,
    const float* __restrict__ qn,
    float* __restrict__ evals, float* __restrict__ Z,
    float* __restrict__ out)
{
    const int e = blockIdx.x * TPB + threadIdx.x;   // NE % TPB == 0
    const int i = ei[e];
    const int j = ei[NE + e];

    const float y0  = ea[(size_t)e * 4 + 0];
    const float y1x = ea[(size_t)e * 4 + 1];
    const float y1y = ea[(size_t)e * 4 + 2];
    const float y1z = ea[(size_t)e * 4 + 3];

    // pack emb (fp16 pairs over a)
    half2v em2[8];
#pragma unroll
    for (int a2 = 0; a2 < 8; ++a2) {
        float e0 = emb[(size_t)e * 16 + 2 * a2];
        float e1 = emb[(size_t)e * 16 + 2 * a2 + 1];
        em2[a2] = half2v{(_Float16)e0, (_Float16)e1};
    }

    // hidden layer h = silu(emb @ W1 / 4), packed into 32 half2 regs
    half2v h2[32];
#pragma unroll
    for (int hh2 = 0; hh2 < 32; ++hh2) {
        float a0 = 0.f, a1 = 0.f;
#pragma unroll
        for (int a2 = 0; a2 < 8; ++a2) {
            a0 = fdot2(em2[a2], w1p[(2 * hh2) * 8 + a2], a0);
            a1 = fdot2(em2[a2], w1p[(2 * hh2 + 1) * 8 + a2], a1);
        }
        float s0 = a0 / (1.f + expf(-a0));
        float s1 = a1 / (1.f + expf(-a1));
        h2[hh2] = half2v{(_Float16)s0, (_Float16)s1};
    }

    const float* xi = x + (size_t)i * 40;

    float ss[8], uu[8], su[4], us[12];
#pragma unroll
    for (int b = 0; b < 8; ++b) { ss[b] = 0.f; uu[b] = 0.f; }
#pragma unroll
    for (int b = 0; b < 4; ++b) su[b] = 0.f;
#pragma unroll
    for (int b = 0; b < 12; ++b) us[b] = 0.f;

    // a in [0,16): ss block (m = a*8+b) and su block (m = 192 + a*4+b)
#pragma unroll 1
    for (int a = 0; a < 16; ++a) {
        float w8[8] = {0.f,0.f,0.f,0.f,0.f,0.f,0.f,0.f};
        float w4[4] = {0.f,0.f,0.f,0.f};
        const half2v* wss = w2p + (size_t)(a * 8) * 32;
        const half2v* wsu = w2p + (size_t)(192 + a * 4) * 32;
#pragma unroll
        for (int hh2 = 0; hh2 < 32; ++hh2) {
            const half2v hv = h2[hh2];
#pragma unroll
            for (int b = 0; b < 8; ++b) w8[b] = fdot2(hv, wss[b * 32 + hh2], w8[b]);
#pragma unroll
            for (int b = 0; b < 4; ++b) w4[b] = fdot2(hv, wsu[b * 32 + hh2], w4[b]);
        }
        const float xv = xi[a];
#pragma unroll
        for (int b = 0; b < 8; ++b) ss[b] += xv * w8[b];
#pragma unroll
        for (int b = 0; b < 4; ++b) su[b] += xv * w4[b];
    }

    // a in [0,8): uu block (m = 128 + a*8+b) and us block (m = 256 + a*4+b)
#pragma unroll 1
    for (int a = 0; a < 8; ++a) {
        float w8[8] = {0.f,0.f,0.f,0.f,0.f,0.f,0.f,0.f};
        float w4[4] = {0.f,0.f,0.f,0.f};
        const half2v* wuu = w2p + (size_t)(128 + a * 8) * 32;
        const half2v* wus = w2p + (size_t)(256 + a * 4) * 32;
#pragma unroll
        for (int hh2 = 0; hh2 < 32; ++hh2) {
            const half2v hv = h2[hh2];
#pragma unroll
            for (int b = 0; b < 8; ++b) w8[b] = fdot2(hv, wuu[b * 32 + hh2], w8[b]);
#pragma unroll
            for (int b = 0; b < 4; ++b) w4[b] = fdot2(hv, wus[b * 32 + hh2], w4[b]);
        }
        const float u0 = xi[16 + a * 3 + 0];
        const float u1 = xi[16 + a * 3 + 1];
        const float u2 = xi[16 + a * 3 + 2];
        const float xy = u0 * y1x + u1 * y1y + u2 * y1z;
#pragma unroll
        for (int b = 0; b < 8; ++b) uu[b] += xy * w8[b];
#pragma unroll
        for (int b = 0; b < 4; ++b) {
            us[b * 3 + 0] += u0 * w4[b];
            us[b * 3 + 1] += u1 * w4[b];
            us[b * 3 + 2] += u2 * w4[b];
        }
    }

    float k0[8], k1[12];
#pragma unroll
    for (int b = 0; b < 8; ++b)
        k0[b] = (ss[b] * y0 * 0.25f + uu[b] * INV_SQRT24) * TP_FOLD;
#pragma unroll
    for (int b = 0; b < 4; ++b) {
        k1[b * 3 + 0] = (su[b] * 0.25f * y1x + us[b * 3 + 0] * INV_SQRT8 * y0) * TP_FOLD;
        k1[b * 3 + 1] = (su[b] * 0.25f * y1y + us[b * 3 + 1] * INV_SQRT8 * y0) * TP_FOLD;
        k1[b * 3 + 2] = (su[b] * 0.25f * y1z + us[b * 3 + 2] * INV_SQRT8 * y0) * TP_FOLD;
    }

    if constexpr (!ISV) {
        const float* qj = qn + (size_t)j * 20;
        float d0 = 0.f;
#pragma unroll
        for (int a = 0; a < 8; ++a) {
            float t = 0.f;
#pragma unroll
            for (int b = 0; b < 8; ++b) t += k0[b] * wd0[a * 8 + b];
            d0 += qj[a] * t;
        }
        float d1 = 0.f;
#pragma unroll
        for (int a = 0; a < 4; ++a)
#pragma unroll
            for (int c = 0; c < 3; ++c) {
                float t = 0.f;
#pragma unroll
                for (int b = 0; b < 4; ++b) t += k1[b * 3 + c] * wd1[a * 4 + b];
                d1 += qj[8 + a * 3 + c] * t;
            }
        const float d = d0 * D0S + d1 * D1S;
        const float len = el[e];
        const float tt = 10.f * (1.f - len / 3.15f);
        float cut = 0.f;
        if (tt > 0.f) cut = expf(-1.f / fmaxf(tt, 1e-6f));
        const float ev = cut * expf(d);
        evals[e] = ev;
        atomicAdd(Z + j, ev);
    } else {
        const float ev = evals[e];
        const float zz = Z[j];
        const float wgt = sqrtf(fmaxf(ev / zz, 0.f));
        float* o = out + (size_t)j * 20;
#pragma unroll
        for (int b = 0; b < 8; ++b) atomicAdd(o + b, wgt * k0[b]);
#pragma unroll
        for (int t = 0; t < 12; ++t) atomicAdd(o + 8 + t, wgt * k1[t]);
    }
}

extern "C" void kernel_launch(void* const* d_in, const int* in_sizes, int n_in,
                              void* d_out, int out_size, void* d_ws, size_t ws_size,
                              hipStream_t stream)
{
    const float* x     = (const float*)d_in[0];
    const int*   eidx  = (const int*)d_in[1];
    const float* eattr = (const float*)d_in[2];
    const float* emb   = (const float*)d_in[3];
    const float* elen  = (const float*)d_in[4];
    const float* wq0   = (const float*)d_in[5];
    const float* wq1   = (const float*)d_in[6];
    const float* wk1   = (const float*)d_in[7];
    const float* wk2   = (const float*)d_in[8];
    const float* wv1   = (const float*)d_in[9];
    const float* wv2   = (const float*)d_in[10];
    const float* wd0   = (const float*)d_in[11];
    const float* wd1   = (const float*)d_in[12];

    float* ws  = (float*)d_ws;
    float* out = (float*)d_out;
    half2v* wk1p = (half2v*)(ws + WK1P_OFF);
    half2v* wv1p = (half2v*)(ws + WV1P_OFF);
    half2v* wk2p = (half2v*)(ws + WK2P_OFF);
    half2v* wv2p = (half2v*)(ws + WV2P_OFF);

    hipMemsetAsync(ws, 0, NN * sizeof(float), stream);                 // Z
    hipMemsetAsync(out, 0, (size_t)out_size * sizeof(float), stream);

    prep_pack<<<9216 / TPB, TPB, 0, stream>>>(wk1, wk2, wv1, wv2,
                                              wk1p, wv1p, wk2p, wv2p);
    prep_q<<<(NN + TPB - 1) / TPB, TPB, 0, stream>>>(x, wq0, wq1, ws + Q_OFF);

    edge_pass<false><<<NE / TPB, TPB, 0, stream>>>(
        x, eidx, eattr, emb, elen, wk1p, wk2p, wd0, wd1,
        ws + Q_OFF, ws + EV_OFF, ws, out);
    edge_pass<true><<<NE / TPB, TPB, 0, stream>>>(
        x, eidx, eattr, emb, elen, wv1p, wv2p, wd0, wd1,
        ws + Q_OFF, ws + EV_OFF, ws, out);
}

// Round 6
// 812.994 us; speedup vs baseline: 1.9947x; 1.1366x over previous
//
#include <hip/hip_runtime.h>
#include <math.h>

#define NN 30000
#define NE 480000
#define TPB 256

// ---- workspace layout (float offsets) ----
#define Q_OFF    30000
#define EV_OFF   630000
#define W1PK_OFF 1110000
#define W1PV_OFF 1110512
#define W2FK_OFF 1111024
#define W2FV_OFF 1120240
// total 1129456 floats (~4.52 MB)

#define INV_SQRT8  0.35355339059327376f
#define TP_FOLD    0.08838834764831845f
#define SIG_SS     0.02209708691207961f   // 0.25*TP_FOLD      (ss block)
#define SIG_UU     0.01804219591217582f   // (1/sqrt24)*TP_FOLD (uu block)
#define SIG_SU     0.02209708691207961f   // 0.25*TP_FOLD      (su block)
#define SIG_US     0.03125f               // (1/sqrt8)*TP_FOLD  (us block)
#define D0S        0.08838834764831845f
#define D1S        0.10206207261596575f

typedef _Float16 half2v __attribute__((ext_vector_type(2)));
typedef _Float16 f16x8  __attribute__((ext_vector_type(8)));
typedef float    f32x4  __attribute__((ext_vector_type(4)));

__device__ __forceinline__ float fdot2(half2v a, half2v b, float c) {
    return __builtin_amdgcn_fdot2(a, b, c, false);
}

// ---------- weight prep: W1 half2-pairs + W2 A-fragment pack (HW-validated map) ----------
__global__ __launch_bounds__(TPB) void prep_pack(
    const float* __restrict__ wk1, const float* __restrict__ wk2,
    const float* __restrict__ wv1, const float* __restrict__ wv2,
    half2v* __restrict__ wk1p, half2v* __restrict__ wv1p,
    _Float16* __restrict__ w2fk, _Float16* __restrict__ w2fv)
{
    int tid = blockIdx.x * TPB + threadIdx.x;   // 4608 exactly
    {
        int p = tid / 2304, rem = tid % 2304;
        int fg = rem >> 6, l = rem & 63;        // fg = t*2+s
        int t = fg >> 1, s = fg & 1;
        int kbase = s * 32 + (l >> 4) * 8;
        int m = t * 16 + (l & 15);
        float sig = (m < 128) ? SIG_SS : (m < 192) ? SIG_UU
                  : (m < 256) ? SIG_SU : SIG_US;
        const float* W2 = p ? wv2 : wk2;
        _Float16* dst = (p ? w2fv : w2fk) + (size_t)(fg * 64 + l) * 8;
#pragma unroll
        for (int jj = 0; jj < 8; ++jj)
            dst[jj] = (_Float16)(W2[(size_t)(kbase + jj) * 288 + m] * sig);
    }
    if (tid < 512) {
        int hh = tid >> 3, a2 = tid & 7;
        wk1p[tid] = half2v{(_Float16)(wk1[(2 * a2) * 64 + hh] * 0.25f),
                           (_Float16)(wk1[(2 * a2 + 1) * 64 + hh] * 0.25f)};
        wv1p[tid] = half2v{(_Float16)(wv1[(2 * a2) * 64 + hh] * 0.25f),
                           (_Float16)(wv1[(2 * a2 + 1) * 64 + hh] * 0.25f)};
    }
}

// ---------- per-node q0 (8) and q1 (4x3), RAW (verbatim round-2 verified) ----------
__global__ __launch_bounds__(TPB) void prep_q(
    const float* __restrict__ x,
    const float* __restrict__ wq0, const float* __restrict__ wq1,
    float* __restrict__ q)
{
    int n = blockIdx.x * TPB + threadIdx.x;
    if (n >= NN) return;
    const float* xr = x + (size_t)n * 40;
    float* o = q + (size_t)n * 20;
#pragma unroll
    for (int b = 0; b < 8; ++b) {
        float acc = 0.f;
#pragma unroll
        for (int a = 0; a < 16; ++a) acc += xr[a] * wq0[a * 8 + b];
        o[b] = acc * 0.25f;
    }
#pragma unroll
    for (int b = 0; b < 4; ++b)
#pragma unroll
        for (int c = 0; c < 3; ++c) {
            float acc = 0.f;
#pragma unroll
            for (int a = 0; a < 8; ++a) acc += xr[16 + a * 3 + c] * wq1[a * 4 + b];
            o[8 + b * 3 + c] = acc * INV_SQRT8;
        }
}

// ---------- bisect kernel: MFMA front half (r4) + serial r2 epilogue ----------
template <bool ISV>
__global__ __launch_bounds__(TPB) void edge_mfma(
    const float* __restrict__ x, const int* __restrict__ ei,
    const float* __restrict__ eattr, const float* __restrict__ emb,
    const float* __restrict__ el,
    const half2v* __restrict__ w1p, const f16x8* __restrict__ w2f,
    const float* __restrict__ wd0, const float* __restrict__ wd1,
    const float* __restrict__ qn,
    float* __restrict__ evals, float* __restrict__ Z,
    float* __restrict__ out)
{
    __shared__ __align__(16) _Float16 sh_h[4][16][72];
    __shared__ _Float16 sh_R[4][16][292];   // R[m][edge], sigma-folded

    const int tid = threadIdx.x;
    const int w = tid >> 6, l = tid & 63, q = l >> 4, n = l & 15;
    const int e = blockIdx.x * 64 + w * 16 + n;
    const int i = ei[e];
    const int j = ei[NE + e];
    const float4 ea = *(const float4*)(eattr + (size_t)e * 4);
    const float y0 = ea.x, y1x = ea.y, y1y = ea.z, y1z = ea.w;

    // ---- h = silu(0.25 * emb @ W1): lane covers hidden q*16..q*16+15 of edge n ----
    half2v em2[8];
    {
        const float4* ep = (const float4*)(emb + (size_t)e * 16);
#pragma unroll
        for (int p = 0; p < 4; ++p) {
            float4 v = ep[p];
            em2[2 * p]     = half2v{(_Float16)v.x, (_Float16)v.y};
            em2[2 * p + 1] = half2v{(_Float16)v.z, (_Float16)v.w};
        }
    }
#pragma unroll
    for (int k2 = 0; k2 < 8; ++k2) {
        float zz[2];
#pragma unroll
        for (int hf = 0; hf < 2; ++hf) {
            int k = q * 16 + 2 * k2 + hf;
            const half2v* wr = w1p + (size_t)k * 8;
            float a0 = 0.f, a1 = 0.f;
#pragma unroll
            for (int a2 = 0; a2 < 4; ++a2) {
                a0 = fdot2(em2[2 * a2], wr[2 * a2], a0);
                a1 = fdot2(em2[2 * a2 + 1], wr[2 * a2 + 1], a1);
            }
            float zv = a0 + a1;
            zz[hf] = zv / (1.f + expf(-zv));
        }
        *(half2v*)&sh_h[w][n][q * 16 + 2 * k2] = half2v{(_Float16)zz[0], (_Float16)zz[1]};
    }
    __syncthreads();

    // ---- GEMM (HW-validated fragment maps): acc[t][r] = R[16t+4q+r][edge n] ----
    f16x8 B0 = *(const f16x8*)&sh_h[w][n][q * 8];
    f16x8 B1 = *(const f16x8*)&sh_h[w][n][32 + q * 8];
    f32x4 acc[18];
#pragma unroll
    for (int t = 0; t < 18; ++t) acc[t] = f32x4{0.f, 0.f, 0.f, 0.f};
#pragma unroll
    for (int t = 0; t < 18; ++t) {
        f16x8 A0 = w2f[(t * 2 + 0) * 64 + l];
        f16x8 A1 = w2f[(t * 2 + 1) * 64 + l];
        acc[t] = __builtin_amdgcn_mfma_f32_16x16x32_f16(A0, B0, acc[t], 0, 0, 0);
        acc[t] = __builtin_amdgcn_mfma_f32_16x16x32_f16(A1, B1, acc[t], 0, 0, 0);
    }

    // ---- dump R to LDS explicitly ----
#pragma unroll
    for (int t = 0; t < 18; ++t)
#pragma unroll
        for (int r = 0; r < 4; ++r)
            sh_R[w][n][t * 16 + 4 * q + r] = (_Float16)acc[t][r];
    __syncthreads();

    if (q != 0) return;

    // ==== serial per-edge epilogue: verbatim round-2-verified code, R from LDS ====
#define RM(m) ((float)sh_R[w][n][(m)])
    const float* xi = x + (size_t)i * 40;

    float ss[8], uu[8], su[4], us[12];
#pragma unroll
    for (int b = 0; b < 8; ++b) { ss[b] = 0.f; uu[b] = 0.f; }
#pragma unroll
    for (int b = 0; b < 4; ++b) su[b] = 0.f;
#pragma unroll
    for (int b = 0; b < 12; ++b) us[b] = 0.f;

#pragma unroll 1
    for (int a = 0; a < 16; ++a) {
        const float xv = xi[a];
#pragma unroll
        for (int b = 0; b < 8; ++b) ss[b] += xv * RM(a * 8 + b);
#pragma unroll
        for (int b = 0; b < 4; ++b) su[b] += xv * RM(192 + a * 4 + b);
    }
#pragma unroll 1
    for (int a = 0; a < 8; ++a) {
        const float u0 = xi[16 + a * 3 + 0];
        const float u1 = xi[16 + a * 3 + 1];
        const float u2 = xi[16 + a * 3 + 2];
        const float xy = u0 * y1x + u1 * y1y + u2 * y1z;
#pragma unroll
        for (int b = 0; b < 8; ++b) uu[b] += xy * RM(128 + a * 8 + b);
#pragma unroll
        for (int b = 0; b < 4; ++b) {
            const float wv = RM(256 + a * 4 + b);
            us[b * 3 + 0] += u0 * wv;
            us[b * 3 + 1] += u1 * wv;
            us[b * 3 + 2] += u2 * wv;
        }
    }

    // sigma already folded into R: k0/k1 need only the y factors
    float k0[8], k1[12];
#pragma unroll
    for (int b = 0; b < 8; ++b) k0[b] = y0 * ss[b] + uu[b];
#pragma unroll
    for (int b = 0; b < 4; ++b) {
        k1[b * 3 + 0] = su[b] * y1x + y0 * us[b * 3 + 0];
        k1[b * 3 + 1] = su[b] * y1y + y0 * us[b * 3 + 1];
        k1[b * 3 + 2] = su[b] * y1z + y0 * us[b * 3 + 2];
    }

    if constexpr (!ISV) {
        const float* qj = qn + (size_t)j * 20;
        float d0 = 0.f;
#pragma unroll
        for (int a = 0; a < 8; ++a) {
            float t = 0.f;
#pragma unroll
            for (int b = 0; b < 8; ++b) t += k0[b] * wd0[a * 8 + b];
            d0 += qj[a] * t;
        }
        float d1 = 0.f;
#pragma unroll
        for (int a = 0; a < 4; ++a)
#pragma unroll
            for (int c = 0; c < 3; ++c) {
                float t = 0.f;
#pragma unroll
                for (int b = 0; b < 4; ++b) t += k1[b * 3 + c] * wd1[a * 4 + b];
                d1 += qj[8 + a * 3 + c] * t;
            }
        const float d = d0 * D0S + d1 * D1S;
        const float len = el[e];
        const float tt = 10.f * (1.f - len / 3.15f);
        float cut = 0.f;
        if (tt > 0.f) cut = expf(-1.f / fmaxf(tt, 1e-6f));
        const float ev = cut * expf(d);
        evals[e] = ev;
        atomicAdd(Z + j, ev);
    } else {
        const float ev = evals[e];
        const float zz = Z[j];
        const float wgt = sqrtf(fmaxf(ev / zz, 0.f));
        float* o = out + (size_t)j * 20;
#pragma unroll
        for (int b = 0; b < 8; ++b) atomicAdd(o + b, wgt * k0[b]);
#pragma unroll
        for (int t = 0; t < 12; ++t) atomicAdd(o + 8 + t, wgt * k1[t]);
    }
#undef RM
}

extern "C" void kernel_launch(void* const* d_in, const int* in_sizes, int n_in,
                              void* d_out, int out_size, void* d_ws, size_t ws_size,
                              hipStream_t stream)
{
    const float* x     = (const float*)d_in[0];
    const int*   eidx  = (const int*)d_in[1];
    const float* eattr = (const float*)d_in[2];
    const float* emb   = (const float*)d_in[3];
    const float* elen  = (const float*)d_in[4];
    const float* wq0   = (const float*)d_in[5];
    const float* wq1   = (const float*)d_in[6];
    const float* wk1   = (const float*)d_in[7];
    const float* wk2   = (const float*)d_in[8];
    const float* wv1   = (const float*)d_in[9];
    const float* wv2   = (const float*)d_in[10];
    const float* wd0   = (const float*)d_in[11];
    const float* wd1   = (const float*)d_in[12];

    float* ws  = (float*)d_ws;
    float* out = (float*)d_out;
    half2v* wk1p = (half2v*)(ws + W1PK_OFF);
    half2v* wv1p = (half2v*)(ws + W1PV_OFF);
    _Float16* w2fk = (_Float16*)(ws + W2FK_OFF);
    _Float16* w2fv = (_Float16*)(ws + W2FV_OFF);

    hipMemsetAsync(ws, 0, NN * sizeof(float), stream);                 // Z
    hipMemsetAsync(out, 0, (size_t)out_size * sizeof(float), stream);

    prep_pack<<<4608 / TPB, TPB, 0, stream>>>(wk1, wk2, wv1, wv2,
                                              wk1p, wv1p, w2fk, w2fv);
    prep_q<<<(NN + TPB - 1) / TPB, TPB, 0, stream>>>(x, wq0, wq1, ws + Q_OFF);

    edge_mfma<false><<<NE / 64, TPB, 0, stream>>>(
        x, eidx, eattr, emb, elen, wk1p, (const f16x8*)w2fk, wd0, wd1,
        ws + Q_OFF, ws + EV_OFF, ws, out);
    edge_mfma<true><<<NE / 64, TPB, 0, stream>>>(
        x, eidx, eattr, emb, elen, wv1p, (const f16x8*)w2fv, wd0, wd1,
        ws + Q_OFF, ws + EV_OFF, ws, out);
}

// Round 7
// 608.835 us; speedup vs baseline: 2.6636x; 1.3353x over previous
//
#include <hip/hip_runtime.h>
#include <math.h>

#define NN 30000
#define NE 480000
#define TPB 256

// ---- workspace layout (float offsets) ----
#define Q_OFF    30000
#define EV_OFF   630000
#define W1PK_OFF 1110000
#define W1PV_OFF 1110512
#define W2FK_OFF 1111024
#define W2FV_OFF 1120240
// total 1129456 floats (~4.52 MB)

#define INV_SQRT8  0.35355339059327376f
#define SIG_SS     0.02209708691207961f   // 0.25 * 1/(8*sqrt2)
#define SIG_UU     0.01804219591217582f   // (1/sqrt24) * 1/(8*sqrt2)
#define SIG_SU     0.02209708691207961f
#define SIG_US     0.03125f               // (1/sqrt8) * 1/(8*sqrt2)
#define D0S        0.08838834764831845f
#define D1S        0.10206207261596575f

typedef _Float16 half2v __attribute__((ext_vector_type(2)));
typedef _Float16 f16x8  __attribute__((ext_vector_type(8)));
typedef float    f32x4  __attribute__((ext_vector_type(4)));

__device__ __forceinline__ float fdot2(half2v a, half2v b, float c) {
    return __builtin_amdgcn_fdot2(a, b, c, false);
}

// ---------- weight prep: W1 half2-pairs + W2 A-fragment pack (HW-validated map) ----------
__global__ __launch_bounds__(TPB) void prep_pack(
    const float* __restrict__ wk1, const float* __restrict__ wk2,
    const float* __restrict__ wv1, const float* __restrict__ wv2,
    half2v* __restrict__ wk1p, half2v* __restrict__ wv1p,
    _Float16* __restrict__ w2fk, _Float16* __restrict__ w2fv)
{
    int tid = blockIdx.x * TPB + threadIdx.x;   // 4608 exactly
    {
        int p = tid / 2304, rem = tid % 2304;
        int fg = rem >> 6, l = rem & 63;        // fg = t*2+s
        int t = fg >> 1, s = fg & 1;
        int kbase = s * 32 + (l >> 4) * 8;
        int m = t * 16 + (l & 15);
        float sig = (m < 128) ? SIG_SS : (m < 192) ? SIG_UU
                  : (m < 256) ? SIG_SU : SIG_US;
        const float* W2 = p ? wv2 : wk2;
        _Float16* dst = (p ? w2fv : w2fk) + (size_t)(fg * 64 + l) * 8;
#pragma unroll
        for (int jj = 0; jj < 8; ++jj)
            dst[jj] = (_Float16)(W2[(size_t)(kbase + jj) * 288 + m] * sig);
    }
    if (tid < 512) {
        int hh = tid >> 3, a2 = tid & 7;
        wk1p[tid] = half2v{(_Float16)(wk1[(2 * a2) * 64 + hh] * 0.25f),
                           (_Float16)(wk1[(2 * a2 + 1) * 64 + hh] * 0.25f)};
        wv1p[tid] = half2v{(_Float16)(wv1[(2 * a2) * 64 + hh] * 0.25f),
                           (_Float16)(wv1[(2 * a2 + 1) * 64 + hh] * 0.25f)};
    }
}

// ---------- per-node q0 (8) and q1 (4x3), RAW (r2-verified) ----------
__global__ __launch_bounds__(TPB) void prep_q(
    const float* __restrict__ x,
    const float* __restrict__ wq0, const float* __restrict__ wq1,
    float* __restrict__ q)
{
    int n = blockIdx.x * TPB + threadIdx.x;
    if (n >= NN) return;
    const float* xr = x + (size_t)n * 40;
    float* o = q + (size_t)n * 20;
#pragma unroll
    for (int b = 0; b < 8; ++b) {
        float acc = 0.f;
#pragma unroll
        for (int a = 0; a < 16; ++a) acc += xr[a] * wq0[a * 8 + b];
        o[b] = acc * 0.25f;
    }
#pragma unroll
    for (int b = 0; b < 4; ++b)
#pragma unroll
        for (int c = 0; c < 3; ++c) {
            float acc = 0.f;
#pragma unroll
            for (int a = 0; a < 8; ++a) acc += xr[16 + a * 3 + c] * wq1[a * 4 + b];
            o[8 + b * 3 + c] = acc * INV_SQRT8;
        }
}

// ---------- MFMA edge pass: verified front half + q-parallel LDS epilogue ----------
template <bool ISV>
__global__ __launch_bounds__(TPB) void edge_mfma(
    const float* __restrict__ x, const int* __restrict__ ei,
    const float* __restrict__ eattr, const float* __restrict__ emb,
    const float* __restrict__ el,
    const half2v* __restrict__ w1p, const f16x8* __restrict__ w2f,
    const float* __restrict__ wd0, const float* __restrict__ wd1,
    const float* __restrict__ qn,
    float* __restrict__ evals, float* __restrict__ Z,
    float* __restrict__ out)
{
    __shared__ __align__(16) _Float16 sh_h[4][16][72];
    __shared__ _Float16 sh_R[4][16][292];   // R[m][edge], sigma-folded
    __shared__ float sh_d[4][16][4];        // score partials per q

    const int tid = threadIdx.x;
    const int w = tid >> 6, l = tid & 63, q = l >> 4, n = l & 15;
    const int e = blockIdx.x * 64 + w * 16 + n;
    const int i = ei[e];
    const int j = ei[NE + e];
    const float4 ea = *(const float4*)(eattr + (size_t)e * 4);
    const float y0 = ea.x, y1x = ea.y, y1y = ea.z, y1z = ea.w;

    // ---- h = silu(0.25 * emb @ W1): lane covers hidden q*16..q*16+15 of edge n ----
    half2v em2[8];
    {
        const float4* ep = (const float4*)(emb + (size_t)e * 16);
#pragma unroll
        for (int p = 0; p < 4; ++p) {
            float4 v = ep[p];
            em2[2 * p]     = half2v{(_Float16)v.x, (_Float16)v.y};
            em2[2 * p + 1] = half2v{(_Float16)v.z, (_Float16)v.w};
        }
    }
#pragma unroll
    for (int k2 = 0; k2 < 8; ++k2) {
        float zz[2];
#pragma unroll
        for (int hf = 0; hf < 2; ++hf) {
            int k = q * 16 + 2 * k2 + hf;
            const half2v* wr = w1p + (size_t)k * 8;
            float a0 = 0.f, a1 = 0.f;
#pragma unroll
            for (int a2 = 0; a2 < 4; ++a2) {
                a0 = fdot2(em2[2 * a2], wr[2 * a2], a0);
                a1 = fdot2(em2[2 * a2 + 1], wr[2 * a2 + 1], a1);
            }
            float zv = a0 + a1;
            zz[hf] = zv / (1.f + expf(-zv));
        }
        *(half2v*)&sh_h[w][n][q * 16 + 2 * k2] = half2v{(_Float16)zz[0], (_Float16)zz[1]};
    }
    __syncthreads();

    // ---- GEMM (HW-validated): acc[t][r] = R[16t+4q+r][edge n] ----
    f16x8 B0 = *(const f16x8*)&sh_h[w][n][q * 8];
    f16x8 B1 = *(const f16x8*)&sh_h[w][n][32 + q * 8];
    f32x4 acc[18];
#pragma unroll
    for (int t = 0; t < 18; ++t) acc[t] = f32x4{0.f, 0.f, 0.f, 0.f};
#pragma unroll
    for (int t = 0; t < 18; ++t) {
        f16x8 A0 = w2f[(t * 2 + 0) * 64 + l];
        f16x8 A1 = w2f[(t * 2 + 1) * 64 + l];
        acc[t] = __builtin_amdgcn_mfma_f32_16x16x32_f16(A0, B0, acc[t], 0, 0, 0);
        acc[t] = __builtin_amdgcn_mfma_f32_16x16x32_f16(A1, B1, acc[t], 0, 0, 0);
    }

    // ---- dump R to LDS (verified mechanism) ----
#pragma unroll
    for (int t = 0; t < 18; ++t)
#pragma unroll
        for (int r = 0; r < 4; ++r)
            sh_R[w][n][t * 16 + 4 * q + r] = (_Float16)acc[t][r];
    __syncthreads();

    // ==== q-parallel epilogue: b-sliced copy of the r6-verified serial code ====
#define RM(m) ((float)sh_R[w][n][(m)])
    const float* xi = x + (size_t)i * 40;

    float k0v[4];          // valid for q<2:  k0[4q + r]
    float k1v[2][3];       // valid for q>=2: k1[2(q-2)+bb][c]
    const int b0 = (q < 2) ? (4 * q) : (2 * (q - 2));

    if (q < 2) {
        float ssv[4] = {0.f, 0.f, 0.f, 0.f};
        float uuv[4] = {0.f, 0.f, 0.f, 0.f};
#pragma unroll
        for (int a = 0; a < 16; ++a) {
            const float xv = xi[a];
#pragma unroll
            for (int r = 0; r < 4; ++r) ssv[r] += xv * RM(a * 8 + b0 + r);
        }
#pragma unroll
        for (int a = 0; a < 8; ++a) {
            const float u0 = xi[16 + a * 3 + 0];
            const float u1 = xi[16 + a * 3 + 1];
            const float u2 = xi[16 + a * 3 + 2];
            const float xy = u0 * y1x + u1 * y1y + u2 * y1z;
#pragma unroll
            for (int r = 0; r < 4; ++r) uuv[r] += xy * RM(128 + a * 8 + b0 + r);
        }
#pragma unroll
        for (int r = 0; r < 4; ++r) k0v[r] = y0 * ssv[r] + uuv[r];
    } else {
        float suv[2] = {0.f, 0.f};
        float usv[2][3] = {{0.f, 0.f, 0.f}, {0.f, 0.f, 0.f}};
#pragma unroll
        for (int a = 0; a < 16; ++a) {
            const float xv = xi[a];
            suv[0] += xv * RM(192 + a * 4 + b0);
            suv[1] += xv * RM(192 + a * 4 + b0 + 1);
        }
#pragma unroll
        for (int a = 0; a < 8; ++a) {
            const float u0 = xi[16 + a * 3 + 0];
            const float u1 = xi[16 + a * 3 + 1];
            const float u2 = xi[16 + a * 3 + 2];
#pragma unroll
            for (int bb = 0; bb < 2; ++bb) {
                const float wv = RM(256 + a * 4 + b0 + bb);
                usv[bb][0] += u0 * wv;
                usv[bb][1] += u1 * wv;
                usv[bb][2] += u2 * wv;
            }
        }
#pragma unroll
        for (int bb = 0; bb < 2; ++bb) {
            k1v[bb][0] = suv[bb] * y1x + y0 * usv[bb][0];
            k1v[bb][1] = suv[bb] * y1y + y0 * usv[bb][1];
            k1v[bb][2] = suv[bb] * y1z + y0 * usv[bb][2];
        }
    }

    if constexpr (!ISV) {
        const float* qj = qn + (size_t)j * 20;
        float pd = 0.f;
        if (q < 2) {
#pragma unroll
            for (int a = 0; a < 8; ++a) {
                float t = 0.f;
#pragma unroll
                for (int r = 0; r < 4; ++r) t += k0v[r] * wd0[a * 8 + b0 + r];
                pd += qj[a] * t;
            }
            pd *= D0S;
        } else {
#pragma unroll
            for (int a = 0; a < 4; ++a)
#pragma unroll
                for (int c = 0; c < 3; ++c) {
                    float t = k1v[0][c] * wd1[a * 4 + b0]
                            + k1v[1][c] * wd1[a * 4 + b0 + 1];
                    pd += qj[8 + 3 * a + c] * t;
                }
            pd *= D1S;
        }
        sh_d[w][n][q] = pd;
        __syncthreads();
        if (q == 0) {
            const float d = sh_d[w][n][0] + sh_d[w][n][1]
                          + sh_d[w][n][2] + sh_d[w][n][3];
            const float len = el[e];
            const float tt = 10.f * (1.f - len / 3.15f);
            float cut = 0.f;
            if (tt > 0.f) cut = expf(-1.f / fmaxf(tt, 1e-6f));
            const float ev = cut * expf(d);
            evals[e] = ev;
            atomicAdd(Z + j, ev);
        }
    } else {
        const float ev = evals[e];
        const float zz = Z[j];
        const float wgt = sqrtf(fmaxf(ev / zz, 0.f));
        float* o = out + (size_t)j * 20;
        if (q < 2) {
#pragma unroll
            for (int r = 0; r < 4; ++r) atomicAdd(o + b0 + r, wgt * k0v[r]);
        } else {
#pragma unroll
            for (int bb = 0; bb < 2; ++bb) {
                atomicAdd(o + 8 + (b0 + bb) * 3 + 0, wgt * k1v[bb][0]);
                atomicAdd(o + 8 + (b0 + bb) * 3 + 1, wgt * k1v[bb][1]);
                atomicAdd(o + 8 + (b0 + bb) * 3 + 2, wgt * k1v[bb][2]);
            }
        }
    }
#undef RM
}

extern "C" void kernel_launch(void* const* d_in, const int* in_sizes, int n_in,
                              void* d_out, int out_size, void* d_ws, size_t ws_size,
                              hipStream_t stream)
{
    const float* x     = (const float*)d_in[0];
    const int*   eidx  = (const int*)d_in[1];
    const float* eattr = (const float*)d_in[2];
    const float* emb   = (const float*)d_in[3];
    const float* elen  = (const float*)d_in[4];
    const float* wq0   = (const float*)d_in[5];
    const float* wq1   = (const float*)d_in[6];
    const float* wk1   = (const float*)d_in[7];
    const float* wk2   = (const float*)d_in[8];
    const float* wv1   = (const float*)d_in[9];
    const float* wv2   = (const float*)d_in[10];
    const float* wd0   = (const float*)d_in[11];
    const float* wd1   = (const float*)d_in[12];

    float* ws  = (float*)d_ws;
    float* out = (float*)d_out;
    half2v* wk1p = (half2v*)(ws + W1PK_OFF);
    half2v* wv1p = (half2v*)(ws + W1PV_OFF);
    _Float16* w2fk = (_Float16*)(ws + W2FK_OFF);
    _Float16* w2fv = (_Float16*)(ws + W2FV_OFF);

    hipMemsetAsync(ws, 0, NN * sizeof(float), stream);                 // Z
    hipMemsetAsync(out, 0, (size_t)out_size * sizeof(float), stream);

    prep_pack<<<4608 / TPB, TPB, 0, stream>>>(wk1, wk2, wv1, wv2,
                                              wk1p, wv1p, w2fk, w2fv);
    prep_q<<<(NN + TPB - 1) / TPB, TPB, 0, stream>>>(x, wq0, wq1, ws + Q_OFF);

    edge_mfma<false><<<NE / 64, TPB, 0, stream>>>(
        x, eidx, eattr, emb, elen, wk1p, (const f16x8*)w2fk, wd0, wd1,
        ws + Q_OFF, ws + EV_OFF, ws, out);
    edge_mfma<true><<<NE / 64, TPB, 0, stream>>>(
        x, eidx, eattr, emb, elen, wv1p, (const f16x8*)w2fv, wd0, wd1,
        ws + Q_OFF, ws + EV_OFF, ws, out);
}

// Round 8
// 554.767 us; speedup vs baseline: 2.9232x; 1.0975x over previous
//
#include <hip/hip_runtime.h>
#include <math.h>

#define NN 30000
#define NE 480000
#define TPB 256
#define ETPB 128

// ---- workspace layout (float offsets) ----
#define Q_OFF    30000
#define EV_OFF   630000
#define W1PK_OFF 1110000
#define W1PV_OFF 1110512
#define W2FK_OFF 1111024
#define W2FV_OFF 1120240
// total 1129456 floats (~4.52 MB)

#define INV_SQRT8  0.35355339059327376f
#define SIG_SS     0.02209708691207961f   // 0.25 * 1/(8*sqrt2)
#define SIG_UU     0.01804219591217582f   // (1/sqrt24) * 1/(8*sqrt2)
#define SIG_SU     0.02209708691207961f
#define SIG_US     0.03125f               // (1/sqrt8) * 1/(8*sqrt2)
#define D0S        0.08838834764831845f
#define D1S        0.10206207261596575f

typedef _Float16 half2v __attribute__((ext_vector_type(2)));
typedef _Float16 f16x4  __attribute__((ext_vector_type(4)));
typedef _Float16 f16x8  __attribute__((ext_vector_type(8)));
typedef float    f32x4  __attribute__((ext_vector_type(4)));

__device__ __forceinline__ float fdot2(half2v a, half2v b, float c) {
    return __builtin_amdgcn_fdot2(a, b, c, false);
}

// ---------- weight prep: W1 half2-pairs + W2 A-fragment pack (HW-validated map) ----------
__global__ __launch_bounds__(TPB) void prep_pack(
    const float* __restrict__ wk1, const float* __restrict__ wk2,
    const float* __restrict__ wv1, const float* __restrict__ wv2,
    half2v* __restrict__ wk1p, half2v* __restrict__ wv1p,
    _Float16* __restrict__ w2fk, _Float16* __restrict__ w2fv)
{
    int tid = blockIdx.x * TPB + threadIdx.x;   // 4608 exactly
    {
        int p = tid / 2304, rem = tid % 2304;
        int fg = rem >> 6, l = rem & 63;        // fg = t*2+s
        int t = fg >> 1, s = fg & 1;
        int kbase = s * 32 + (l >> 4) * 8;
        int m = t * 16 + (l & 15);
        float sig = (m < 128) ? SIG_SS : (m < 192) ? SIG_UU
                  : (m < 256) ? SIG_SU : SIG_US;
        const float* W2 = p ? wv2 : wk2;
        _Float16* dst = (p ? w2fv : w2fk) + (size_t)(fg * 64 + l) * 8;
#pragma unroll
        for (int jj = 0; jj < 8; ++jj)
            dst[jj] = (_Float16)(W2[(size_t)(kbase + jj) * 288 + m] * sig);
    }
    if (tid < 512) {
        int hh = tid >> 3, a2 = tid & 7;
        wk1p[tid] = half2v{(_Float16)(wk1[(2 * a2) * 64 + hh] * 0.25f),
                           (_Float16)(wk1[(2 * a2 + 1) * 64 + hh] * 0.25f)};
        wv1p[tid] = half2v{(_Float16)(wv1[(2 * a2) * 64 + hh] * 0.25f),
                           (_Float16)(wv1[(2 * a2 + 1) * 64 + hh] * 0.25f)};
    }
}

// ---------- per-node q0 (8) and q1 (4x3), RAW (r2-verified) ----------
__global__ __launch_bounds__(TPB) void prep_q(
    const float* __restrict__ x,
    const float* __restrict__ wq0, const float* __restrict__ wq1,
    float* __restrict__ q)
{
    int n = blockIdx.x * TPB + threadIdx.x;
    if (n >= NN) return;
    const float* xr = x + (size_t)n * 40;
    float* o = q + (size_t)n * 20;
#pragma unroll
    for (int b = 0; b < 8; ++b) {
        float acc = 0.f;
#pragma unroll
        for (int a = 0; a < 16; ++a) acc += xr[a] * wq0[a * 8 + b];
        o[b] = acc * 0.25f;
    }
#pragma unroll
    for (int b = 0; b < 4; ++b)
#pragma unroll
        for (int c = 0; c < 3; ++c) {
            float acc = 0.f;
#pragma unroll
            for (int a = 0; a < 8; ++a) acc += xr[16 + a * 3 + c] * wq1[a * 4 + b];
            o[8 + b * 3 + c] = acc * INV_SQRT8;
        }
}

// ---------- MFMA edge pass: 2 waves/block, h unioned into R, vector LDS ----------
template <bool ISV>
__global__ __launch_bounds__(ETPB, 4) void edge_mfma(
    const float* __restrict__ x, const int* __restrict__ ei,
    const float* __restrict__ eattr, const float* __restrict__ emb,
    const float* __restrict__ el,
    const half2v* __restrict__ w1p, const f16x8* __restrict__ w2f,
    const float* __restrict__ wd0, const float* __restrict__ wd1,
    const float* __restrict__ qn,
    float* __restrict__ evals, float* __restrict__ Z,
    float* __restrict__ out)
{
    // R[m][edge] rows, 304-half stride (16B-aligned rows); h staged in halfs [0..63]
    __shared__ __align__(16) _Float16 sh_R[2][16][304];
    __shared__ float sh_d[2][16][4];

    const int tid = threadIdx.x;
    const int w = tid >> 6, l = tid & 63, q = l >> 4, n = l & 15;
    const int e = blockIdx.x * 32 + w * 16 + n;
    const int i = ei[e];
    const int j = ei[NE + e];
    const float4 ea = *(const float4*)(eattr + (size_t)e * 4);
    const float y0 = ea.x, y1x = ea.y, y1y = ea.z, y1z = ea.w;

    // ---- h = silu(0.25 * emb @ W1): lane covers hidden q*16..q*16+15 of edge n ----
    half2v em2[8];
    {
        const float4* ep = (const float4*)(emb + (size_t)e * 16);
#pragma unroll
        for (int p = 0; p < 4; ++p) {
            float4 v = ep[p];
            em2[2 * p]     = half2v{(_Float16)v.x, (_Float16)v.y};
            em2[2 * p + 1] = half2v{(_Float16)v.z, (_Float16)v.w};
        }
    }
#pragma unroll
    for (int k4 = 0; k4 < 4; ++k4) {
        f16x4 hv;
#pragma unroll
        for (int ii = 0; ii < 4; ++ii) {
            const int k = q * 16 + 4 * k4 + ii;
            const half2v* wr = w1p + (size_t)k * 8;
            float a0 = 0.f, a1 = 0.f;
#pragma unroll
            for (int a2 = 0; a2 < 4; ++a2) {
                a0 = fdot2(em2[2 * a2], wr[2 * a2], a0);
                a1 = fdot2(em2[2 * a2 + 1], wr[2 * a2 + 1], a1);
            }
            const float zv = a0 + a1;
            const float s = zv * __builtin_amdgcn_rcpf(1.f + __expf(-zv));
            hv[ii] = (_Float16)s;
        }
        *(f16x4*)&sh_R[w][n][q * 16 + 4 * k4] = hv;
    }
    __syncthreads();

    // ---- GEMM (HW-validated): acc[t][r] = R[16t+4q+r][edge n] ----
    f16x8 B0 = *(const f16x8*)&sh_R[w][n][q * 8];
    f16x8 B1 = *(const f16x8*)&sh_R[w][n][32 + q * 8];
    f32x4 acc[18];
#pragma unroll
    for (int t = 0; t < 18; ++t) acc[t] = f32x4{0.f, 0.f, 0.f, 0.f};
#pragma unroll
    for (int t = 0; t < 18; ++t) {
        f16x8 A0 = w2f[(t * 2 + 0) * 64 + l];
        f16x8 A1 = w2f[(t * 2 + 1) * 64 + l];
        acc[t] = __builtin_amdgcn_mfma_f32_16x16x32_f16(A0, B0, acc[t], 0, 0, 0);
        acc[t] = __builtin_amdgcn_mfma_f32_16x16x32_f16(A1, B1, acc[t], 0, 0, 0);
    }

    // ---- dump R (rows 16t+4q..+3 contiguous -> one b64 write per tile) ----
    // (safe vs h-region aliasing: write data depends on B0/B1 reads; in-wave DS order)
#pragma unroll
    for (int t = 0; t < 18; ++t) {
        f16x4 rv = {(_Float16)acc[t][0], (_Float16)acc[t][1],
                    (_Float16)acc[t][2], (_Float16)acc[t][3]};
        *(f16x4*)&sh_R[w][n][t * 16 + 4 * q] = rv;
    }
    __syncthreads();

    // ==== q-parallel epilogue (b-sliced, r7-verified algebra, vector LDS reads) ====
    float xr[40];
    {
        const float4* xp = (const float4*)(x + (size_t)i * 40);
#pragma unroll
        for (int p = 0; p < 10; ++p) {
            float4 v = xp[p];
            xr[4 * p] = v.x; xr[4 * p + 1] = v.y;
            xr[4 * p + 2] = v.z; xr[4 * p + 3] = v.w;
        }
    }

    float k0v[4];          // valid for q<2:  k0[4q + r]
    float k1v[2][3];       // valid for q>=2: k1[2(q-2)+bb][c]
    const int b0 = (q < 2) ? (4 * q) : (2 * (q - 2));

    if (q < 2) {
        float ssv[4] = {0.f, 0.f, 0.f, 0.f};
        float uuv[4] = {0.f, 0.f, 0.f, 0.f};
#pragma unroll
        for (int a = 0; a < 16; ++a) {
            const f16x4 rv = *(const f16x4*)&sh_R[w][n][a * 8 + b0];
            const float xv = xr[a];
#pragma unroll
            for (int r = 0; r < 4; ++r) ssv[r] += xv * (float)rv[r];
        }
#pragma unroll
        for (int a = 0; a < 8; ++a) {
            const float xy = xr[16 + a * 3] * y1x + xr[17 + a * 3] * y1y
                           + xr[18 + a * 3] * y1z;
            const f16x4 rv = *(const f16x4*)&sh_R[w][n][128 + a * 8 + b0];
#pragma unroll
            for (int r = 0; r < 4; ++r) uuv[r] += xy * (float)rv[r];
        }
#pragma unroll
        for (int r = 0; r < 4; ++r) k0v[r] = y0 * ssv[r] + uuv[r];
    } else {
        float suv[2] = {0.f, 0.f};
        float usv[2][3] = {{0.f, 0.f, 0.f}, {0.f, 0.f, 0.f}};
#pragma unroll
        for (int a = 0; a < 16; ++a) {
            const half2v rv = *(const half2v*)&sh_R[w][n][192 + a * 4 + b0];
            suv[0] += xr[a] * (float)rv[0];
            suv[1] += xr[a] * (float)rv[1];
        }
#pragma unroll
        for (int a = 0; a < 8; ++a) {
            const half2v rv = *(const half2v*)&sh_R[w][n][256 + a * 4 + b0];
#pragma unroll
            for (int bb = 0; bb < 2; ++bb) {
                const float wv = (float)rv[bb];
                usv[bb][0] += xr[16 + a * 3] * wv;
                usv[bb][1] += xr[17 + a * 3] * wv;
                usv[bb][2] += xr[18 + a * 3] * wv;
            }
        }
#pragma unroll
        for (int bb = 0; bb < 2; ++bb) {
            k1v[bb][0] = suv[bb] * y1x + y0 * usv[bb][0];
            k1v[bb][1] = suv[bb] * y1y + y0 * usv[bb][1];
            k1v[bb][2] = suv[bb] * y1z + y0 * usv[bb][2];
        }
    }

    if constexpr (!ISV) {
        const float* qj = qn + (size_t)j * 20;
        float pd = 0.f;
        if (q < 2) {
#pragma unroll
            for (int a = 0; a < 8; ++a) {
                float t = 0.f;
#pragma unroll
                for (int r = 0; r < 4; ++r) t += k0v[r] * wd0[a * 8 + b0 + r];
                pd += qj[a] * t;
            }
            pd *= D0S;
        } else {
#pragma unroll
            for (int a = 0; a < 4; ++a)
#pragma unroll
                for (int c = 0; c < 3; ++c) {
                    float t = k1v[0][c] * wd1[a * 4 + b0]
                            + k1v[1][c] * wd1[a * 4 + b0 + 1];
                    pd += qj[8 + 3 * a + c] * t;
                }
            pd *= D1S;
        }
        sh_d[w][n][q] = pd;
        __syncthreads();
        if (q == 0) {
            const float d = sh_d[w][n][0] + sh_d[w][n][1]
                          + sh_d[w][n][2] + sh_d[w][n][3];
            const float len = el[e];
            const float tt = 10.f * (1.f - len / 3.15f);
            float cut = 0.f;
            if (tt > 0.f) cut = __expf(-1.f / fmaxf(tt, 1e-6f));
            const float ev = cut * __expf(d);
            evals[e] = ev;
            atomicAdd(Z + j, ev);
        }
    } else {
        const float ev = evals[e];
        const float zz = Z[j];
        const float wgt = sqrtf(fmaxf(ev / zz, 0.f));
        float* o = out + (size_t)j * 20;
        if (q < 2) {
#pragma unroll
            for (int r = 0; r < 4; ++r) atomicAdd(o + b0 + r, wgt * k0v[r]);
        } else {
#pragma unroll
            for (int bb = 0; bb < 2; ++bb) {
                atomicAdd(o + 8 + (b0 + bb) * 3 + 0, wgt * k1v[bb][0]);
                atomicAdd(o + 8 + (b0 + bb) * 3 + 1, wgt * k1v[bb][1]);
                atomicAdd(o + 8 + (b0 + bb) * 3 + 2, wgt * k1v[bb][2]);
            }
        }
    }
}

extern "C" void kernel_launch(void* const* d_in, const int* in_sizes, int n_in,
                              void* d_out, int out_size, void* d_ws, size_t ws_size,
                              hipStream_t stream)
{
    const float* x     = (const float*)d_in[0];
    const int*   eidx  = (const int*)d_in[1];
    const float* eattr = (const float*)d_in[2];
    const float* emb   = (const float*)d_in[3];
    const float* elen  = (const float*)d_in[4];
    const float* wq0   = (const float*)d_in[5];
    const float* wq1   = (const float*)d_in[6];
    const float* wk1   = (const float*)d_in[7];
    const float* wk2   = (const float*)d_in[8];
    const float* wv1   = (const float*)d_in[9];
    const float* wv2   = (const float*)d_in[10];
    const float* wd0   = (const float*)d_in[11];
    const float* wd1   = (const float*)d_in[12];

    float* ws  = (float*)d_ws;
    float* out = (float*)d_out;
    half2v* wk1p = (half2v*)(ws + W1PK_OFF);
    half2v* wv1p = (half2v*)(ws + W1PV_OFF);
    _Float16* w2fk = (_Float16*)(ws + W2FK_OFF);
    _Float16* w2fv = (_Float16*)(ws + W2FV_OFF);

    hipMemsetAsync(ws, 0, NN * sizeof(float), stream);                 // Z
    hipMemsetAsync(out, 0, (size_t)out_size * sizeof(float), stream);

    prep_pack<<<4608 / TPB, TPB, 0, stream>>>(wk1, wk2, wv1, wv2,
                                              wk1p, wv1p, w2fk, w2fv);
    prep_q<<<(NN + TPB - 1) / TPB, TPB, 0, stream>>>(x, wq0, wq1, ws + Q_OFF);

    edge_mfma<false><<<NE / 32, ETPB, 0, stream>>>(
        x, eidx, eattr, emb, elen, wk1p, (const f16x8*)w2fk, wd0, wd1,
        ws + Q_OFF, ws + EV_OFF, ws, out);
    edge_mfma<true><<<NE / 32, ETPB, 0, stream>>>(
        x, eidx, eattr, emb, elen, wv1p, (const f16x8*)w2fv, wd0, wd1,
        ws + Q_OFF, ws + EV_OFF, ws, out);
}

// Round 9
// 429.128 us; speedup vs baseline: 3.7791x; 1.2928x over previous
//
#include <hip/hip_runtime.h>
#include <math.h>

#define NN 30000
#define NE 480000
#define TPB 256
#define ETPB 128

// ---- fallback (r8) workspace layout (float offsets) ----
#define Q_OFF    30000
#define EV_OFF   630000
#define W1PK_OFF 1110000
#define W1PV_OFF 1110512
#define W2FK_OFF 1111024
#define W2FV_OFF 1120240

// ---- new CSR-path workspace layout (float offsets) ----
#define NQ_OFF    0           // 600000 q vectors
#define NW1K_OFF  600000      // 512
#define NW1V_OFF  600512      // 512
#define NW2K_OFF  601024      // 9216
#define NW2V_OFF  610240      // 9216
#define NCNT_OFF  619456      // 30000 int
#define NOFF_OFF  649456      // 30008 int
#define NC2_OFF   679464      // 30000 int
#define NPOS_OFF  709464      // 480000 int
#define NEVS_OFF  1189464     // 480000 f32
#define NVSC_OFF  1669464     // 9600000 halfs
#define NTOT      6469464     // floats (~25.9 MB)

#define INV_SQRT8  0.35355339059327376f
#define SIG_SS     0.02209708691207961f
#define SIG_UU     0.01804219591217582f
#define SIG_SU     0.02209708691207961f
#define SIG_US     0.03125f
#define D0S        0.08838834764831845f
#define D1S        0.10206207261596575f

typedef _Float16 half2v __attribute__((ext_vector_type(2)));
typedef _Float16 f16x4  __attribute__((ext_vector_type(4)));
typedef _Float16 f16x8  __attribute__((ext_vector_type(8)));
typedef float    f32x4  __attribute__((ext_vector_type(4)));

__device__ __forceinline__ float fdot2(half2v a, half2v b, float c) {
    return __builtin_amdgcn_fdot2(a, b, c, false);
}

// ---------- weight prep (HW-validated A-fragment map) ----------
__global__ __launch_bounds__(TPB) void prep_pack(
    const float* __restrict__ wk1, const float* __restrict__ wk2,
    const float* __restrict__ wv1, const float* __restrict__ wv2,
    half2v* __restrict__ wk1p, half2v* __restrict__ wv1p,
    _Float16* __restrict__ w2fk, _Float16* __restrict__ w2fv)
{
    int tid = blockIdx.x * TPB + threadIdx.x;   // 4608 exactly
    {
        int p = tid / 2304, rem = tid % 2304;
        int fg = rem >> 6, l = rem & 63;
        int t = fg >> 1, s = fg & 1;
        int kbase = s * 32 + (l >> 4) * 8;
        int m = t * 16 + (l & 15);
        float sig = (m < 128) ? SIG_SS : (m < 192) ? SIG_UU
                  : (m < 256) ? SIG_SU : SIG_US;
        const float* W2 = p ? wv2 : wk2;
        _Float16* dst = (p ? w2fv : w2fk) + (size_t)(fg * 64 + l) * 8;
#pragma unroll
        for (int jj = 0; jj < 8; ++jj)
            dst[jj] = (_Float16)(W2[(size_t)(kbase + jj) * 288 + m] * sig);
    }
    if (tid < 512) {
        int hh = tid >> 3, a2 = tid & 7;
        wk1p[tid] = half2v{(_Float16)(wk1[(2 * a2) * 64 + hh] * 0.25f),
                           (_Float16)(wk1[(2 * a2 + 1) * 64 + hh] * 0.25f)};
        wv1p[tid] = half2v{(_Float16)(wv1[(2 * a2) * 64 + hh] * 0.25f),
                           (_Float16)(wv1[(2 * a2 + 1) * 64 + hh] * 0.25f)};
    }
}

// ---------- per-node q vectors (r2-verified) ----------
__global__ __launch_bounds__(TPB) void prep_q(
    const float* __restrict__ x,
    const float* __restrict__ wq0, const float* __restrict__ wq1,
    float* __restrict__ q)
{
    int n = blockIdx.x * TPB + threadIdx.x;
    if (n >= NN) return;
    const float* xr = x + (size_t)n * 40;
    float* o = q + (size_t)n * 20;
#pragma unroll
    for (int b = 0; b < 8; ++b) {
        float acc = 0.f;
#pragma unroll
        for (int a = 0; a < 16; ++a) acc += xr[a] * wq0[a * 8 + b];
        o[b] = acc * 0.25f;
    }
#pragma unroll
    for (int b = 0; b < 4; ++b)
#pragma unroll
        for (int c = 0; c < 3; ++c) {
            float acc = 0.f;
#pragma unroll
            for (int a = 0; a < 8; ++a) acc += xr[16 + a * 3 + c] * wq1[a * 4 + b];
            o[8 + b * 3 + c] = acc * INV_SQRT8;
        }
}

// ---------- CSR build ----------
__global__ __launch_bounds__(TPB) void hist_k(const int* __restrict__ ei,
                                              int* __restrict__ cnt)
{
    int e = blockIdx.x * TPB + threadIdx.x;
    if (e < NE) atomicAdd(cnt + ei[NE + e], 1);
}

__global__ __launch_bounds__(1024) void scan_k(const int* __restrict__ cnt,
                                               int* __restrict__ offs)
{
    __shared__ int part[1024];
    const int t = threadIdx.x;
    int local[30];
    int s = 0;
#pragma unroll
    for (int k = 0; k < 30; ++k) {
        int idx = t * 30 + k;
        local[k] = s;
        s += (idx < NN) ? cnt[idx] : 0;
    }
    part[t] = s;
    __syncthreads();
    for (int off = 1; off < 1024; off <<= 1) {
        int v = (t >= off) ? part[t - off] : 0;
        __syncthreads();
        part[t] += v;
        __syncthreads();
    }
    int tbase = (t == 0) ? 0 : part[t - 1];
#pragma unroll
    for (int k = 0; k < 30; ++k) {
        int idx = t * 30 + k;
        if (idx < NN) offs[idx] = tbase + local[k];
    }
    if (t == 1023) offs[NN] = part[1023];
}

__global__ __launch_bounds__(TPB) void rank_k(const int* __restrict__ ei,
                                              const int* __restrict__ offs,
                                              int* __restrict__ c2,
                                              int* __restrict__ pos)
{
    int e = blockIdx.x * TPB + threadIdx.x;
    if (e < NE) {
        int j = ei[NE + e];
        pos[e] = offs[j] + atomicAdd(c2 + j, 1);
    }
}

// ---------- fused k+v edge kernel (verified front half; stores to CSR slots) ----------
__global__ __launch_bounds__(ETPB, 4) void edge_fused(
    const float* __restrict__ x, const int* __restrict__ ei,
    const float* __restrict__ eattr, const float* __restrict__ emb,
    const float* __restrict__ el,
    const half2v* __restrict__ w1pk, const f16x8* __restrict__ w2fk,
    const half2v* __restrict__ w1pv, const f16x8* __restrict__ w2fv,
    const float* __restrict__ wd0, const float* __restrict__ wd1,
    const float* __restrict__ qn, const int* __restrict__ pos,
    float* __restrict__ evs, _Float16* __restrict__ vsc)
{
    __shared__ __align__(16) _Float16 sh_R[2][16][296];  // 148 dw stride: 2-way only
    __shared__ float sh_d[2][16][4];

    const int tid = threadIdx.x;
    const int w = tid >> 6, l = tid & 63, q = l >> 4, n = l & 15;
    const int e = blockIdx.x * 32 + w * 16 + n;
    const int i = ei[e];
    const int j = ei[NE + e];
    const int pe = pos[e];
    const float4 ea = *(const float4*)(eattr + (size_t)e * 4);
    const float y0 = ea.x, y1x = ea.y, y1y = ea.z, y1z = ea.w;
    const int b0 = (q < 2) ? (4 * q) : (2 * (q - 2));

    // ================= K PASS =================
    {
        half2v em2[8];
        const float4* ep = (const float4*)(emb + (size_t)e * 16);
#pragma unroll
        for (int p = 0; p < 4; ++p) {
            float4 v = ep[p];
            em2[2 * p]     = half2v{(_Float16)v.x, (_Float16)v.y};
            em2[2 * p + 1] = half2v{(_Float16)v.z, (_Float16)v.w};
        }
#pragma unroll
        for (int k4 = 0; k4 < 4; ++k4) {
            f16x4 hv;
#pragma unroll
            for (int ii = 0; ii < 4; ++ii) {
                const int k = q * 16 + 4 * k4 + ii;
                const half2v* wr = w1pk + (size_t)k * 8;
                float a0 = 0.f, a1 = 0.f;
#pragma unroll
                for (int a2 = 0; a2 < 4; ++a2) {
                    a0 = fdot2(em2[2 * a2], wr[2 * a2], a0);
                    a1 = fdot2(em2[2 * a2 + 1], wr[2 * a2 + 1], a1);
                }
                const float zv = a0 + a1;
                hv[ii] = (_Float16)(zv * __builtin_amdgcn_rcpf(1.f + __expf(-zv)));
            }
            *(f16x4*)&sh_R[w][n][q * 16 + 4 * k4] = hv;
        }
    }
    __syncthreads();
    {
        f16x8 B0 = *(const f16x8*)&sh_R[w][n][q * 8];
        f16x8 B1 = *(const f16x8*)&sh_R[w][n][32 + q * 8];
        f32x4 acc[18];
#pragma unroll
        for (int t = 0; t < 18; ++t) acc[t] = f32x4{0.f, 0.f, 0.f, 0.f};
#pragma unroll
        for (int t = 0; t < 18; ++t) {
            f16x8 A0 = w2fk[(t * 2 + 0) * 64 + l];
            f16x8 A1 = w2fk[(t * 2 + 1) * 64 + l];
            acc[t] = __builtin_amdgcn_mfma_f32_16x16x32_f16(A0, B0, acc[t], 0, 0, 0);
            acc[t] = __builtin_amdgcn_mfma_f32_16x16x32_f16(A1, B1, acc[t], 0, 0, 0);
        }
#pragma unroll
        for (int t = 0; t < 18; ++t) {
            f16x4 rv = {(_Float16)acc[t][0], (_Float16)acc[t][1],
                        (_Float16)acc[t][2], (_Float16)acc[t][3]};
            *(f16x4*)&sh_R[w][n][t * 16 + 4 * q] = rv;
        }
    }
    __syncthreads();
    // ---- k epilogue: score partials (b-sliced, r7/r8-verified algebra) ----
    {
        float xr[40];
        const float4* xp = (const float4*)(x + (size_t)i * 40);
#pragma unroll
        for (int p = 0; p < 10; ++p) {
            float4 v = xp[p];
            xr[4 * p] = v.x; xr[4 * p + 1] = v.y;
            xr[4 * p + 2] = v.z; xr[4 * p + 3] = v.w;
        }
        const float* qj = qn + (size_t)j * 20;
        float pd = 0.f;
        if (q < 2) {
            float ssv[4] = {0.f, 0.f, 0.f, 0.f};
            float uuv[4] = {0.f, 0.f, 0.f, 0.f};
#pragma unroll
            for (int a = 0; a < 16; ++a) {
                const f16x4 rv = *(const f16x4*)&sh_R[w][n][a * 8 + b0];
#pragma unroll
                for (int r = 0; r < 4; ++r) ssv[r] += xr[a] * (float)rv[r];
            }
#pragma unroll
            for (int a = 0; a < 8; ++a) {
                const float xy = xr[16 + a * 3] * y1x + xr[17 + a * 3] * y1y
                               + xr[18 + a * 3] * y1z;
                const f16x4 rv = *(const f16x4*)&sh_R[w][n][128 + a * 8 + b0];
#pragma unroll
                for (int r = 0; r < 4; ++r) uuv[r] += xy * (float)rv[r];
            }
#pragma unroll
            for (int a = 0; a < 8; ++a) {
                float t = 0.f;
#pragma unroll
                for (int r = 0; r < 4; ++r)
                    t += (y0 * ssv[r] + uuv[r]) * wd0[a * 8 + b0 + r];
                pd += qj[a] * t;
            }
            pd *= D0S;
        } else {
            float suv[2] = {0.f, 0.f};
            float usv[2][3] = {{0.f, 0.f, 0.f}, {0.f, 0.f, 0.f}};
#pragma unroll
            for (int a = 0; a < 16; ++a) {
                const half2v rv = *(const half2v*)&sh_R[w][n][192 + a * 4 + b0];
                suv[0] += xr[a] * (float)rv[0];
                suv[1] += xr[a] * (float)rv[1];
            }
#pragma unroll
            for (int a = 0; a < 8; ++a) {
                const half2v rv = *(const half2v*)&sh_R[w][n][256 + a * 4 + b0];
#pragma unroll
                for (int bb = 0; bb < 2; ++bb) {
                    const float wv = (float)rv[bb];
                    usv[bb][0] += xr[16 + a * 3] * wv;
                    usv[bb][1] += xr[17 + a * 3] * wv;
                    usv[bb][2] += xr[18 + a * 3] * wv;
                }
            }
            float k1v[2][3];
#pragma unroll
            for (int bb = 0; bb < 2; ++bb) {
                k1v[bb][0] = suv[bb] * y1x + y0 * usv[bb][0];
                k1v[bb][1] = suv[bb] * y1y + y0 * usv[bb][1];
                k1v[bb][2] = suv[bb] * y1z + y0 * usv[bb][2];
            }
#pragma unroll
            for (int a = 0; a < 4; ++a)
#pragma unroll
                for (int c = 0; c < 3; ++c) {
                    float t = k1v[0][c] * wd1[a * 4 + b0]
                            + k1v[1][c] * wd1[a * 4 + b0 + 1];
                    pd += qj[8 + 3 * a + c] * t;
                }
            pd *= D1S;
        }
        sh_d[w][n][q] = pd;
    }
    __syncthreads();
    if (q == 0) {
        const float d = sh_d[w][n][0] + sh_d[w][n][1]
                      + sh_d[w][n][2] + sh_d[w][n][3];
        const float len = el[e];
        const float tt = 10.f * (1.f - len / 3.15f);
        float cut = 0.f;
        if (tt > 0.f) cut = __expf(-1.f / fmaxf(tt, 1e-6f));
        evs[pe] = cut * __expf(d);
    }
    __syncthreads();   // all sh_R reads done before v-pass overwrites

    // ================= V PASS =================
    {
        half2v em2[8];
        const float4* ep = (const float4*)(emb + (size_t)e * 16);
#pragma unroll
        for (int p = 0; p < 4; ++p) {
            float4 v = ep[p];
            em2[2 * p]     = half2v{(_Float16)v.x, (_Float16)v.y};
            em2[2 * p + 1] = half2v{(_Float16)v.z, (_Float16)v.w};
        }
#pragma unroll
        for (int k4 = 0; k4 < 4; ++k4) {
            f16x4 hv;
#pragma unroll
            for (int ii = 0; ii < 4; ++ii) {
                const int k = q * 16 + 4 * k4 + ii;
                const half2v* wr = w1pv + (size_t)k * 8;
                float a0 = 0.f, a1 = 0.f;
#pragma unroll
                for (int a2 = 0; a2 < 4; ++a2) {
                    a0 = fdot2(em2[2 * a2], wr[2 * a2], a0);
                    a1 = fdot2(em2[2 * a2 + 1], wr[2 * a2 + 1], a1);
                }
                const float zv = a0 + a1;
                hv[ii] = (_Float16)(zv * __builtin_amdgcn_rcpf(1.f + __expf(-zv)));
            }
            *(f16x4*)&sh_R[w][n][q * 16 + 4 * k4] = hv;
        }
    }
    __syncthreads();
    {
        f16x8 B0 = *(const f16x8*)&sh_R[w][n][q * 8];
        f16x8 B1 = *(const f16x8*)&sh_R[w][n][32 + q * 8];
        f32x4 acc[18];
#pragma unroll
        for (int t = 0; t < 18; ++t) acc[t] = f32x4{0.f, 0.f, 0.f, 0.f};
#pragma unroll
        for (int t = 0; t < 18; ++t) {
            f16x8 A0 = w2fv[(t * 2 + 0) * 64 + l];
            f16x8 A1 = w2fv[(t * 2 + 1) * 64 + l];
            acc[t] = __builtin_amdgcn_mfma_f32_16x16x32_f16(A0, B0, acc[t], 0, 0, 0);
            acc[t] = __builtin_amdgcn_mfma_f32_16x16x32_f16(A1, B1, acc[t], 0, 0, 0);
        }
#pragma unroll
        for (int t = 0; t < 18; ++t) {
            f16x4 rv = {(_Float16)acc[t][0], (_Float16)acc[t][1],
                        (_Float16)acc[t][2], (_Float16)acc[t][3]};
            *(f16x4*)&sh_R[w][n][t * 16 + 4 * q] = rv;
        }
    }
    __syncthreads();
    // ---- v epilogue: store 20-half record at CSR slot ----
    {
        float xr[40];
        const float4* xp = (const float4*)(x + (size_t)i * 40);
#pragma unroll
        for (int p = 0; p < 10; ++p) {
            float4 v = xp[p];
            xr[4 * p] = v.x; xr[4 * p + 1] = v.y;
            xr[4 * p + 2] = v.z; xr[4 * p + 3] = v.w;
        }
        _Float16* rec = vsc + (size_t)pe * 20;
        if (q < 2) {
            float ssv[4] = {0.f, 0.f, 0.f, 0.f};
            float uuv[4] = {0.f, 0.f, 0.f, 0.f};
#pragma unroll
            for (int a = 0; a < 16; ++a) {
                const f16x4 rv = *(const f16x4*)&sh_R[w][n][a * 8 + b0];
#pragma unroll
                for (int r = 0; r < 4; ++r) ssv[r] += xr[a] * (float)rv[r];
            }
#pragma unroll
            for (int a = 0; a < 8; ++a) {
                const float xy = xr[16 + a * 3] * y1x + xr[17 + a * 3] * y1y
                               + xr[18 + a * 3] * y1z;
                const f16x4 rv = *(const f16x4*)&sh_R[w][n][128 + a * 8 + b0];
#pragma unroll
                for (int r = 0; r < 4; ++r) uuv[r] += xy * (float)rv[r];
            }
            f16x4 o;
#pragma unroll
            for (int r = 0; r < 4; ++r) o[r] = (_Float16)(y0 * ssv[r] + uuv[r]);
            *(f16x4*)&rec[b0] = o;
        } else {
            float suv[2] = {0.f, 0.f};
            float usv[2][3] = {{0.f, 0.f, 0.f}, {0.f, 0.f, 0.f}};
#pragma unroll
            for (int a = 0; a < 16; ++a) {
                const half2v rv = *(const half2v*)&sh_R[w][n][192 + a * 4 + b0];
                suv[0] += xr[a] * (float)rv[0];
                suv[1] += xr[a] * (float)rv[1];
            }
#pragma unroll
            for (int a = 0; a < 8; ++a) {
                const half2v rv = *(const half2v*)&sh_R[w][n][256 + a * 4 + b0];
#pragma unroll
                for (int bb = 0; bb < 2; ++bb) {
                    const float wv = (float)rv[bb];
                    usv[bb][0] += xr[16 + a * 3] * wv;
                    usv[bb][1] += xr[17 + a * 3] * wv;
                    usv[bb][2] += xr[18 + a * 3] * wv;
                }
            }
            float k1v[2][3];
#pragma unroll
            for (int bb = 0; bb < 2; ++bb) {
                k1v[bb][0] = suv[bb] * y1x + y0 * usv[bb][0];
                k1v[bb][1] = suv[bb] * y1y + y0 * usv[bb][1];
                k1v[bb][2] = suv[bb] * y1z + y0 * usv[bb][2];
            }
            const int base = 8 + b0 * 3;   // q=2 -> 8, q=3 -> 14
            *(half2v*)&rec[base]     = half2v{(_Float16)k1v[0][0], (_Float16)k1v[0][1]};
            *(half2v*)&rec[base + 2] = half2v{(_Float16)k1v[0][2], (_Float16)k1v[1][0]};
            *(half2v*)&rec[base + 4] = half2v{(_Float16)k1v[1][1], (_Float16)k1v[1][2]};
        }
    }
}

// ---------- node gather: one wave per node, zero atomics ----------
__global__ __launch_bounds__(TPB) void node_gather(
    const int* __restrict__ offs,
    const float* __restrict__ evs, const _Float16* __restrict__ vsc,
    float* __restrict__ out)
{
    const int wv = threadIdx.x >> 6, lane = threadIdx.x & 63;
    const int j = blockIdx.x * 4 + wv;
    if (j >= NN) return;
    const int o0 = offs[j], o1 = offs[j + 1];
    const int cnt = o1 - o0;

    float s = 0.f;
    for (int t = lane; t < cnt; t += 64) s += evs[o0 + t];
#pragma unroll
    for (int d = 1; d < 64; d <<= 1) s += __shfl_xor(s, d);
    const float invZ = (s > 0.f) ? (1.f / s) : 0.f;

    float acc = 0.f;
    for (int t = 0; t < cnt; ++t) {
        const float ev = evs[o0 + t];
        const float wgt = sqrtf(fmaxf(ev * invZ, 0.f));
        if (lane < 20) acc += wgt * (float)vsc[(size_t)(o0 + t) * 20 + lane];
    }
    if (lane < 20) out[(size_t)j * 20 + lane] = acc;
}

// ================= fallback (r8, verified) =================
template <bool ISV>
__global__ __launch_bounds__(ETPB, 4) void edge_mfma(
    const float* __restrict__ x, const int* __restrict__ ei,
    const float* __restrict__ eattr, const float* __restrict__ emb,
    const float* __restrict__ el,
    const half2v* __restrict__ w1p, const f16x8* __restrict__ w2f,
    const float* __restrict__ wd0, const float* __restrict__ wd1,
    const float* __restrict__ qn,
    float* __restrict__ evals, float* __restrict__ Z,
    float* __restrict__ out)
{
    __shared__ __align__(16) _Float16 sh_R[2][16][296];
    __shared__ float sh_d[2][16][4];

    const int tid = threadIdx.x;
    const int w = tid >> 6, l = tid & 63, q = l >> 4, n = l & 15;
    const int e = blockIdx.x * 32 + w * 16 + n;
    const int i = ei[e];
    const int j = ei[NE + e];
    const float4 ea = *(const float4*)(eattr + (size_t)e * 4);
    const float y0 = ea.x, y1x = ea.y, y1y = ea.z, y1z = ea.w;

    half2v em2[8];
    {
        const float4* ep = (const float4*)(emb + (size_t)e * 16);
#pragma unroll
        for (int p = 0; p < 4; ++p) {
            float4 v = ep[p];
            em2[2 * p]     = half2v{(_Float16)v.x, (_Float16)v.y};
            em2[2 * p + 1] = half2v{(_Float16)v.z, (_Float16)v.w};
        }
    }
#pragma unroll
    for (int k4 = 0; k4 < 4; ++k4) {
        f16x4 hv;
#pragma unroll
        for (int ii = 0; ii < 4; ++ii) {
            const int k = q * 16 + 4 * k4 + ii;
            const half2v* wr = w1p + (size_t)k * 8;
            float a0 = 0.f, a1 = 0.f;
#pragma unroll
            for (int a2 = 0; a2 < 4; ++a2) {
                a0 = fdot2(em2[2 * a2], wr[2 * a2], a0);
                a1 = fdot2(em2[2 * a2 + 1], wr[2 * a2 + 1], a1);
            }
            const float zv = a0 + a1;
            hv[ii] = (_Float16)(zv * __builtin_amdgcn_rcpf(1.f + __expf(-zv)));
        }
        *(f16x4*)&sh_R[w][n][q * 16 + 4 * k4] = hv;
    }
    __syncthreads();

    f16x8 B0 = *(const f16x8*)&sh_R[w][n][q * 8];
    f16x8 B1 = *(const f16x8*)&sh_R[w][n][32 + q * 8];
    f32x4 acc[18];
#pragma unroll
    for (int t = 0; t < 18; ++t) acc[t] = f32x4{0.f, 0.f, 0.f, 0.f};
#pragma unroll
    for (int t = 0; t < 18; ++t) {
        f16x8 A0 = w2f[(t * 2 + 0) * 64 + l];
        f16x8 A1 = w2f[(t * 2 + 1) * 64 + l];
        acc[t] = __builtin_amdgcn_mfma_f32_16x16x32_f16(A0, B0, acc[t], 0, 0, 0);
        acc[t] = __builtin_amdgcn_mfma_f32_16x16x32_f16(A1, B1, acc[t], 0, 0, 0);
    }
#pragma unroll
    for (int t = 0; t < 18; ++t) {
        f16x4 rv = {(_Float16)acc[t][0], (_Float16)acc[t][1],
                    (_Float16)acc[t][2], (_Float16)acc[t][3]};
        *(f16x4*)&sh_R[w][n][t * 16 + 4 * q] = rv;
    }
    __syncthreads();

    float xr[40];
    {
        const float4* xp = (const float4*)(x + (size_t)i * 40);
#pragma unroll
        for (int p = 0; p < 10; ++p) {
            float4 v = xp[p];
            xr[4 * p] = v.x; xr[4 * p + 1] = v.y;
            xr[4 * p + 2] = v.z; xr[4 * p + 3] = v.w;
        }
    }

    float k0v[4];
    float k1v[2][3];
    const int b0 = (q < 2) ? (4 * q) : (2 * (q - 2));

    if (q < 2) {
        float ssv[4] = {0.f, 0.f, 0.f, 0.f};
        float uuv[4] = {0.f, 0.f, 0.f, 0.f};
#pragma unroll
        for (int a = 0; a < 16; ++a) {
            const f16x4 rv = *(const f16x4*)&sh_R[w][n][a * 8 + b0];
#pragma unroll
            for (int r = 0; r < 4; ++r) ssv[r] += xr[a] * (float)rv[r];
        }
#pragma unroll
        for (int a = 0; a < 8; ++a) {
            const float xy = xr[16 + a * 3] * y1x + xr[17 + a * 3] * y1y
                           + xr[18 + a * 3] * y1z;
            const f16x4 rv = *(const f16x4*)&sh_R[w][n][128 + a * 8 + b0];
#pragma unroll
            for (int r = 0; r < 4; ++r) uuv[r] += xy * (float)rv[r];
        }
#pragma unroll
        for (int r = 0; r < 4; ++r) k0v[r] = y0 * ssv[r] + uuv[r];
    } else {
        float suv[2] = {0.f, 0.f};
        float usv[2][3] = {{0.f, 0.f, 0.f}, {0.f, 0.f, 0.f}};
#pragma unroll
        for (int a = 0; a < 16; ++a) {
            const half2v rv = *(const half2v*)&sh_R[w][n][192 + a * 4 + b0];
            suv[0] += xr[a] * (float)rv[0];
            suv[1] += xr[a] * (float)rv[1];
        }
#pragma unroll
        for (int a = 0; a < 8; ++a) {
            const half2v rv = *(const half2v*)&sh_R[w][n][256 + a * 4 + b0];
#pragma unroll
            for (int bb = 0; bb < 2; ++bb) {
                const float wv = (float)rv[bb];
                usv[bb][0] += xr[16 + a * 3] * wv;
                usv[bb][1] += xr[17 + a * 3] * wv;
                usv[bb][2] += xr[18 + a * 3] * wv;
            }
        }
#pragma unroll
        for (int bb = 0; bb < 2; ++bb) {
            k1v[bb][0] = suv[bb] * y1x + y0 * usv[bb][0];
            k1v[bb][1] = suv[bb] * y1y + y0 * usv[bb][1];
            k1v[bb][2] = suv[bb] * y1z + y0 * usv[bb][2];
        }
    }

    if constexpr (!ISV) {
        const float* qj = qn + (size_t)j * 20;
        float pd = 0.f;
        if (q < 2) {
#pragma unroll
            for (int a = 0; a < 8; ++a) {
                float t = 0.f;
#pragma unroll
                for (int r = 0; r < 4; ++r) t += k0v[r] * wd0[a * 8 + b0 + r];
                pd += qj[a] * t;
            }
            pd *= D0S;
        } else {
#pragma unroll
            for (int a = 0; a < 4; ++a)
#pragma unroll
                for (int c = 0; c < 3; ++c) {
                    float t = k1v[0][c] * wd1[a * 4 + b0]
                            + k1v[1][c] * wd1[a * 4 + b0 + 1];
                    pd += qj[8 + 3 * a + c] * t;
                }
            pd *= D1S;
        }
        sh_d[w][n][q] = pd;
        __syncthreads();
        if (q == 0) {
            const float d = sh_d[w][n][0] + sh_d[w][n][1]
                          + sh_d[w][n][2] + sh_d[w][n][3];
            const float len = el[e];
            const float tt = 10.f * (1.f - len / 3.15f);
            float cut = 0.f;
            if (tt > 0.f) cut = __expf(-1.f / fmaxf(tt, 1e-6f));
            const float ev = cut * __expf(d);
            evals[e] = ev;
            atomicAdd(Z + j, ev);
        }
    } else {
        const float ev = evals[e];
        const float zz = Z[j];
        const float wgt = sqrtf(fmaxf(ev / zz, 0.f));
        float* o = out + (size_t)j * 20;
        if (q < 2) {
#pragma unroll
            for (int r = 0; r < 4; ++r) atomicAdd(o + b0 + r, wgt * k0v[r]);
        } else {
#pragma unroll
            for (int bb = 0; bb < 2; ++bb) {
                atomicAdd(o + 8 + (b0 + bb) * 3 + 0, wgt * k1v[bb][0]);
                atomicAdd(o + 8 + (b0 + bb) * 3 + 1, wgt * k1v[bb][1]);
                atomicAdd(o + 8 + (b0 + bb) * 3 + 2, wgt * k1v[bb][2]);
            }
        }
    }
}

extern "C" void kernel_launch(void* const* d_in, const int* in_sizes, int n_in,
                              void* d_out, int out_size, void* d_ws, size_t ws_size,
                              hipStream_t stream)
{
    const float* x     = (const float*)d_in[0];
    const int*   eidx  = (const int*)d_in[1];
    const float* eattr = (const float*)d_in[2];
    const float* emb   = (const float*)d_in[3];
    const float* elen  = (const float*)d_in[4];
    const float* wq0   = (const float*)d_in[5];
    const float* wq1   = (const float*)d_in[6];
    const float* wk1   = (const float*)d_in[7];
    const float* wk2   = (const float*)d_in[8];
    const float* wv1   = (const float*)d_in[9];
    const float* wv2   = (const float*)d_in[10];
    const float* wd0   = (const float*)d_in[11];
    const float* wd1   = (const float*)d_in[12];

    float* ws  = (float*)d_ws;
    float* out = (float*)d_out;

    if (ws_size >= (size_t)NTOT * sizeof(float)) {
        // ---------- CSR path ----------
        half2v* w1pk = (half2v*)(ws + NW1K_OFF);
        half2v* w1pv = (half2v*)(ws + NW1V_OFF);
        _Float16* w2fk = (_Float16*)(ws + NW2K_OFF);
        _Float16* w2fv = (_Float16*)(ws + NW2V_OFF);
        int* cnt  = (int*)(ws + NCNT_OFF);
        int* offs = (int*)(ws + NOFF_OFF);
        int* c2   = (int*)(ws + NC2_OFF);
        int* pos  = (int*)(ws + NPOS_OFF);
        float* evs = ws + NEVS_OFF;
        _Float16* vsc = (_Float16*)(ws + NVSC_OFF);

        hipMemsetAsync(cnt, 0, NN * sizeof(int), stream);
        hipMemsetAsync(c2, 0, NN * sizeof(int), stream);

        prep_pack<<<4608 / TPB, TPB, 0, stream>>>(wk1, wk2, wv1, wv2,
                                                  w1pk, w1pv, w2fk, w2fv);
        prep_q<<<(NN + TPB - 1) / TPB, TPB, 0, stream>>>(x, wq0, wq1, ws + NQ_OFF);
        hist_k<<<(NE + TPB - 1) / TPB, TPB, 0, stream>>>(eidx, cnt);
        scan_k<<<1, 1024, 0, stream>>>(cnt, offs);
        rank_k<<<(NE + TPB - 1) / TPB, TPB, 0, stream>>>(eidx, offs, c2, pos);

        edge_fused<<<NE / 32, ETPB, 0, stream>>>(
            x, eidx, eattr, emb, elen,
            w1pk, (const f16x8*)w2fk, w1pv, (const f16x8*)w2fv,
            wd0, wd1, ws + NQ_OFF, pos, evs, vsc);

        node_gather<<<(NN + 3) / 4, TPB, 0, stream>>>(offs, evs, vsc, out);
    } else {
        // ---------- fallback: r8 verified path ----------
        half2v* wk1p = (half2v*)(ws + W1PK_OFF);
        half2v* wv1p = (half2v*)(ws + W1PV_OFF);
        _Float16* w2fk = (_Float16*)(ws + W2FK_OFF);
        _Float16* w2fv = (_Float16*)(ws + W2FV_OFF);

        hipMemsetAsync(ws, 0, NN * sizeof(float), stream);
        hipMemsetAsync(out, 0, (size_t)out_size * sizeof(float), stream);

        prep_pack<<<4608 / TPB, TPB, 0, stream>>>(wk1, wk2, wv1, wv2,
                                                  wk1p, wv1p, w2fk, w2fv);
        prep_q<<<(NN + TPB - 1) / TPB, TPB, 0, stream>>>(x, wq0, wq1, ws + Q_OFF);

        edge_mfma<false><<<NE / 32, ETPB, 0, stream>>>(
            x, eidx, eattr, emb, elen, wk1p, (const f16x8*)w2fk, wd0, wd1,
            ws + Q_OFF, ws + EV_OFF, ws, out);
        edge_mfma<true><<<NE / 32, ETPB, 0, stream>>>(
            x, eidx, eattr, emb, elen, wv1p, (const f16x8*)w2fv, wd0, wd1,
            ws + Q_OFF, ws + EV_OFF, ws, out);
    }
}

// Round 10
// 412.853 us; speedup vs baseline: 3.9281x; 1.0394x over previous
//
#include <hip/hip_runtime.h>
#include <math.h>

#define NN 30000
#define NE 480000
#define TPB 256
#define ETPB 128

// ---- CSR-path workspace layout (float offsets) ----
#define NQ_OFF    0           // 600000 q vectors
#define NW1K_OFF  600000      // 512
#define NW1V_OFF  600512      // 512
#define NW2K_OFF  601024      // 9216
#define NW2V_OFF  610240      // 9216
#define NCNT_OFF  619456      // 30000 int
#define NOFF_OFF  649456      // 30008 int
#define NC2_OFF   679464      // 30000 int
#define NPOS_OFF  709464      // 480000 int
#define NEVS_OFF  1189464     // 480000 f32
#define NVSC_OFF  1669464     // 9600000 halfs
#define NTOT      6469464     // floats (~25.9 MB)

#define INV_SQRT8  0.35355339059327376f
#define SIG_SS     0.02209708691207961f
#define SIG_UU     0.01804219591217582f
#define SIG_SU     0.02209708691207961f
#define SIG_US     0.03125f
#define D0S        0.08838834764831845f
#define D1S        0.10206207261596575f

typedef _Float16 half2v __attribute__((ext_vector_type(2)));
typedef _Float16 f16x4  __attribute__((ext_vector_type(4)));
typedef _Float16 f16x8  __attribute__((ext_vector_type(8)));
typedef float    f32x4  __attribute__((ext_vector_type(4)));

__device__ __forceinline__ float fdot2(half2v a, half2v b, float c) {
    return __builtin_amdgcn_fdot2(a, b, c, false);
}

// ---------- fused prep: weight pack (blocks 0..17) + q vectors (18..135) + zero (136..)
__global__ __launch_bounds__(TPB) void prep_all(
    const float* __restrict__ x,
    const float* __restrict__ wq0, const float* __restrict__ wq1,
    const float* __restrict__ wk1, const float* __restrict__ wk2,
    const float* __restrict__ wv1, const float* __restrict__ wv2,
    half2v* __restrict__ w1pk, half2v* __restrict__ w1pv,
    _Float16* __restrict__ w2fk, _Float16* __restrict__ w2fv,
    float* __restrict__ q, int* __restrict__ cnt, int* __restrict__ c2)
{
    const int b = blockIdx.x;
    if (b < 18) {
        // ---- weight pack (HW-validated A-fragment map; r9-verified) ----
        int tid = b * TPB + threadIdx.x;   // 4608 exactly
        {
            int p = tid / 2304, rem = tid % 2304;
            int fg = rem >> 6, l = rem & 63;
            int t = fg >> 1, s = fg & 1;
            int kbase = s * 32 + (l >> 4) * 8;
            int m = t * 16 + (l & 15);
            float sig = (m < 128) ? SIG_SS : (m < 192) ? SIG_UU
                      : (m < 256) ? SIG_SU : SIG_US;
            const float* W2 = p ? wv2 : wk2;
            _Float16* dst = (p ? w2fv : w2fk) + (size_t)(fg * 64 + l) * 8;
#pragma unroll
            for (int jj = 0; jj < 8; ++jj)
                dst[jj] = (_Float16)(W2[(size_t)(kbase + jj) * 288 + m] * sig);
        }
        if (tid < 512) {
            int hh = tid >> 3, a2 = tid & 7;
            w1pk[tid] = half2v{(_Float16)(wk1[(2 * a2) * 64 + hh] * 0.25f),
                               (_Float16)(wk1[(2 * a2 + 1) * 64 + hh] * 0.25f)};
            w1pv[tid] = half2v{(_Float16)(wv1[(2 * a2) * 64 + hh] * 0.25f),
                               (_Float16)(wv1[(2 * a2 + 1) * 64 + hh] * 0.25f)};
        }
    } else if (b < 136) {
        // ---- per-node q vectors (r2-verified) ----
        int n = (b - 18) * TPB + threadIdx.x;
        if (n >= NN) return;
        const float* xr = x + (size_t)n * 40;
        float* o = q + (size_t)n * 20;
#pragma unroll
        for (int bb = 0; bb < 8; ++bb) {
            float acc = 0.f;
#pragma unroll
            for (int a = 0; a < 16; ++a) acc += xr[a] * wq0[a * 8 + bb];
            o[bb] = acc * 0.25f;
        }
#pragma unroll
        for (int bb = 0; bb < 4; ++bb)
#pragma unroll
            for (int c = 0; c < 3; ++c) {
                float acc = 0.f;
#pragma unroll
                for (int a = 0; a < 8; ++a) acc += xr[16 + a * 3 + c] * wq1[a * 4 + bb];
                o[8 + bb * 3 + c] = acc * INV_SQRT8;
            }
    } else {
        int idx = (b - 136) * TPB + threadIdx.x;
        if (idx < NN) { cnt[idx] = 0; c2[idx] = 0; }
    }
}

// ---------- CSR build ----------
__global__ __launch_bounds__(TPB) void hist_k(const int* __restrict__ ei,
                                              int* __restrict__ cnt)
{
    int e = blockIdx.x * TPB + threadIdx.x;
    if (e < NE) atomicAdd(cnt + ei[NE + e], 1);
}

__global__ __launch_bounds__(1024) void scan_k(const int* __restrict__ cnt,
                                               int* __restrict__ offs)
{
    __shared__ int part[1024];
    const int t = threadIdx.x;
    int local[30];
    int s = 0;
#pragma unroll
    for (int k = 0; k < 30; ++k) {
        int idx = t * 30 + k;
        local[k] = s;
        s += (idx < NN) ? cnt[idx] : 0;
    }
    part[t] = s;
    __syncthreads();
    for (int off = 1; off < 1024; off <<= 1) {
        int v = (t >= off) ? part[t - off] : 0;
        __syncthreads();
        part[t] += v;
        __syncthreads();
    }
    int tbase = (t == 0) ? 0 : part[t - 1];
#pragma unroll
    for (int k = 0; k < 30; ++k) {
        int idx = t * 30 + k;
        if (idx < NN) offs[idx] = tbase + local[k];
    }
    if (t == 1023) offs[NN] = part[1023];
}

__global__ __launch_bounds__(TPB) void rank_k(const int* __restrict__ ei,
                                              const int* __restrict__ offs,
                                              int* __restrict__ c2,
                                              int* __restrict__ pos)
{
    int e = blockIdx.x * TPB + threadIdx.x;
    if (e < NE) {
        int j = ei[NE + e];
        pos[e] = offs[j] + atomicAdd(c2 + j, 1);
    }
}

// ---------- fused k+v edge kernel (r9-verified; + qj register prefetch) ----------
__global__ __launch_bounds__(ETPB, 4) void edge_fused(
    const float* __restrict__ x, const int* __restrict__ ei,
    const float* __restrict__ eattr, const float* __restrict__ emb,
    const float* __restrict__ el,
    const half2v* __restrict__ w1pk, const f16x8* __restrict__ w2fk,
    const half2v* __restrict__ w1pv, const f16x8* __restrict__ w2fv,
    const float* __restrict__ wd0, const float* __restrict__ wd1,
    const float* __restrict__ qn, const int* __restrict__ pos,
    float* __restrict__ evs, _Float16* __restrict__ vsc)
{
    __shared__ __align__(16) _Float16 sh_R[2][16][296];
    __shared__ float sh_d[2][16][4];

    const int tid = threadIdx.x;
    const int w = tid >> 6, l = tid & 63, q = l >> 4, n = l & 15;
    const int e = blockIdx.x * 32 + w * 16 + n;
    const int i = ei[e];
    const int j = ei[NE + e];
    const int pe = pos[e];
    const float4 ea = *(const float4*)(eattr + (size_t)e * 4);
    const float y0 = ea.x, y1x = ea.y, y1y = ea.z, y1z = ea.w;
    const int b0 = (q < 2) ? (4 * q) : (2 * (q - 2));

    // prefetch q_j into registers (hidden behind h + GEMM)
    float qj[20];
    {
        const float4* qp = (const float4*)(qn + (size_t)j * 20);
#pragma unroll
        for (int p = 0; p < 5; ++p) {
            float4 v = qp[p];
            qj[4 * p] = v.x; qj[4 * p + 1] = v.y;
            qj[4 * p + 2] = v.z; qj[4 * p + 3] = v.w;
        }
    }

    // ================= K PASS =================
    {
        half2v em2[8];
        const float4* ep = (const float4*)(emb + (size_t)e * 16);
#pragma unroll
        for (int p = 0; p < 4; ++p) {
            float4 v = ep[p];
            em2[2 * p]     = half2v{(_Float16)v.x, (_Float16)v.y};
            em2[2 * p + 1] = half2v{(_Float16)v.z, (_Float16)v.w};
        }
#pragma unroll
        for (int k4 = 0; k4 < 4; ++k4) {
            f16x4 hv;
#pragma unroll
            for (int ii = 0; ii < 4; ++ii) {
                const int k = q * 16 + 4 * k4 + ii;
                const half2v* wr = w1pk + (size_t)k * 8;
                float a0 = 0.f, a1 = 0.f;
#pragma unroll
                for (int a2 = 0; a2 < 4; ++a2) {
                    a0 = fdot2(em2[2 * a2], wr[2 * a2], a0);
                    a1 = fdot2(em2[2 * a2 + 1], wr[2 * a2 + 1], a1);
                }
                const float zv = a0 + a1;
                hv[ii] = (_Float16)(zv * __builtin_amdgcn_rcpf(1.f + __expf(-zv)));
            }
            *(f16x4*)&sh_R[w][n][q * 16 + 4 * k4] = hv;
        }
    }
    __syncthreads();
    {
        f16x8 B0 = *(const f16x8*)&sh_R[w][n][q * 8];
        f16x8 B1 = *(const f16x8*)&sh_R[w][n][32 + q * 8];
        f32x4 acc[18];
#pragma unroll
        for (int t = 0; t < 18; ++t) acc[t] = f32x4{0.f, 0.f, 0.f, 0.f};
#pragma unroll
        for (int t = 0; t < 18; ++t) {
            f16x8 A0 = w2fk[(t * 2 + 0) * 64 + l];
            f16x8 A1 = w2fk[(t * 2 + 1) * 64 + l];
            acc[t] = __builtin_amdgcn_mfma_f32_16x16x32_f16(A0, B0, acc[t], 0, 0, 0);
            acc[t] = __builtin_amdgcn_mfma_f32_16x16x32_f16(A1, B1, acc[t], 0, 0, 0);
        }
#pragma unroll
        for (int t = 0; t < 18; ++t) {
            f16x4 rv = {(_Float16)acc[t][0], (_Float16)acc[t][1],
                        (_Float16)acc[t][2], (_Float16)acc[t][3]};
            *(f16x4*)&sh_R[w][n][t * 16 + 4 * q] = rv;
        }
    }
    __syncthreads();
    // ---- k epilogue: score partials (b-sliced, r7/r8/r9-verified algebra) ----
    {
        float xr[40];
        const float4* xp = (const float4*)(x + (size_t)i * 40);
#pragma unroll
        for (int p = 0; p < 10; ++p) {
            float4 v = xp[p];
            xr[4 * p] = v.x; xr[4 * p + 1] = v.y;
            xr[4 * p + 2] = v.z; xr[4 * p + 3] = v.w;
        }
        float pd = 0.f;
        if (q < 2) {
            float ssv[4] = {0.f, 0.f, 0.f, 0.f};
            float uuv[4] = {0.f, 0.f, 0.f, 0.f};
#pragma unroll
            for (int a = 0; a < 16; ++a) {
                const f16x4 rv = *(const f16x4*)&sh_R[w][n][a * 8 + b0];
#pragma unroll
                for (int r = 0; r < 4; ++r) ssv[r] += xr[a] * (float)rv[r];
            }
#pragma unroll
            for (int a = 0; a < 8; ++a) {
                const float xy = xr[16 + a * 3] * y1x + xr[17 + a * 3] * y1y
                               + xr[18 + a * 3] * y1z;
                const f16x4 rv = *(const f16x4*)&sh_R[w][n][128 + a * 8 + b0];
#pragma unroll
                for (int r = 0; r < 4; ++r) uuv[r] += xy * (float)rv[r];
            }
#pragma unroll
            for (int a = 0; a < 8; ++a) {
                float t = 0.f;
#pragma unroll
                for (int r = 0; r < 4; ++r)
                    t += (y0 * ssv[r] + uuv[r]) * wd0[a * 8 + b0 + r];
                pd += qj[a] * t;
            }
            pd *= D0S;
        } else {
            float suv[2] = {0.f, 0.f};
            float usv[2][3] = {{0.f, 0.f, 0.f}, {0.f, 0.f, 0.f}};
#pragma unroll
            for (int a = 0; a < 16; ++a) {
                const half2v rv = *(const half2v*)&sh_R[w][n][192 + a * 4 + b0];
                suv[0] += xr[a] * (float)rv[0];
                suv[1] += xr[a] * (float)rv[1];
            }
#pragma unroll
            for (int a = 0; a < 8; ++a) {
                const half2v rv = *(const half2v*)&sh_R[w][n][256 + a * 4 + b0];
#pragma unroll
                for (int bb = 0; bb < 2; ++bb) {
                    const float wv = (float)rv[bb];
                    usv[bb][0] += xr[16 + a * 3] * wv;
                    usv[bb][1] += xr[17 + a * 3] * wv;
                    usv[bb][2] += xr[18 + a * 3] * wv;
                }
            }
            float k1v[2][3];
#pragma unroll
            for (int bb = 0; bb < 2; ++bb) {
                k1v[bb][0] = suv[bb] * y1x + y0 * usv[bb][0];
                k1v[bb][1] = suv[bb] * y1y + y0 * usv[bb][1];
                k1v[bb][2] = suv[bb] * y1z + y0 * usv[bb][2];
            }
#pragma unroll
            for (int a = 0; a < 4; ++a)
#pragma unroll
                for (int c = 0; c < 3; ++c) {
                    float t = k1v[0][c] * wd1[a * 4 + b0]
                            + k1v[1][c] * wd1[a * 4 + b0 + 1];
                    pd += qj[8 + 3 * a + c] * t;
                }
            pd *= D1S;
        }
        sh_d[w][n][q] = pd;
    }
    __syncthreads();
    if (q == 0) {
        const float d = sh_d[w][n][0] + sh_d[w][n][1]
                      + sh_d[w][n][2] + sh_d[w][n][3];
        const float len = el[e];
        const float tt = 10.f * (1.f - len / 3.15f);
        float cut = 0.f;
        if (tt > 0.f) cut = __expf(-1.f / fmaxf(tt, 1e-6f));
        evs[pe] = cut * __expf(d);
    }
    __syncthreads();   // all sh_R reads done before v-pass overwrites

    // ================= V PASS =================
    {
        half2v em2[8];
        const float4* ep = (const float4*)(emb + (size_t)e * 16);
#pragma unroll
        for (int p = 0; p < 4; ++p) {
            float4 v = ep[p];
            em2[2 * p]     = half2v{(_Float16)v.x, (_Float16)v.y};
            em2[2 * p + 1] = half2v{(_Float16)v.z, (_Float16)v.w};
        }
#pragma unroll
        for (int k4 = 0; k4 < 4; ++k4) {
            f16x4 hv;
#pragma unroll
            for (int ii = 0; ii < 4; ++ii) {
                const int k = q * 16 + 4 * k4 + ii;
                const half2v* wr = w1pv + (size_t)k * 8;
                float a0 = 0.f, a1 = 0.f;
#pragma unroll
                for (int a2 = 0; a2 < 4; ++a2) {
                    a0 = fdot2(em2[2 * a2], wr[2 * a2], a0);
                    a1 = fdot2(em2[2 * a2 + 1], wr[2 * a2 + 1], a1);
                }
                const float zv = a0 + a1;
                hv[ii] = (_Float16)(zv * __builtin_amdgcn_rcpf(1.f + __expf(-zv)));
            }
            *(f16x4*)&sh_R[w][n][q * 16 + 4 * k4] = hv;
        }
    }
    __syncthreads();
    {
        f16x8 B0 = *(const f16x8*)&sh_R[w][n][q * 8];
        f16x8 B1 = *(const f16x8*)&sh_R[w][n][32 + q * 8];
        f32x4 acc[18];
#pragma unroll
        for (int t = 0; t < 18; ++t) acc[t] = f32x4{0.f, 0.f, 0.f, 0.f};
#pragma unroll
        for (int t = 0; t < 18; ++t) {
            f16x8 A0 = w2fv[(t * 2 + 0) * 64 + l];
            f16x8 A1 = w2fv[(t * 2 + 1) * 64 + l];
            acc[t] = __builtin_amdgcn_mfma_f32_16x16x32_f16(A0, B0, acc[t], 0, 0, 0);
            acc[t] = __builtin_amdgcn_mfma_f32_16x16x32_f16(A1, B1, acc[t], 0, 0, 0);
        }
#pragma unroll
        for (int t = 0; t < 18; ++t) {
            f16x4 rv = {(_Float16)acc[t][0], (_Float16)acc[t][1],
                        (_Float16)acc[t][2], (_Float16)acc[t][3]};
            *(f16x4*)&sh_R[w][n][t * 16 + 4 * q] = rv;
        }
    }
    __syncthreads();
    // ---- v epilogue: store 20-half record at CSR slot ----
    {
        float xr[40];
        const float4* xp = (const float4*)(x + (size_t)i * 40);
#pragma unroll
        for (int p = 0; p < 10; ++p) {
            float4 v = xp[p];
            xr[4 * p] = v.x; xr[4 * p + 1] = v.y;
            xr[4 * p + 2] = v.z; xr[4 * p + 3] = v.w;
        }
        _Float16* rec = vsc + (size_t)pe * 20;
        if (q < 2) {
            float ssv[4] = {0.f, 0.f, 0.f, 0.f};
            float uuv[4] = {0.f, 0.f, 0.f, 0.f};
#pragma unroll
            for (int a = 0; a < 16; ++a) {
                const f16x4 rv = *(const f16x4*)&sh_R[w][n][a * 8 + b0];
#pragma unroll
                for (int r = 0; r < 4; ++r) ssv[r] += xr[a] * (float)rv[r];
            }
#pragma unroll
            for (int a = 0; a < 8; ++a) {
                const float xy = xr[16 + a * 3] * y1x + xr[17 + a * 3] * y1y
                               + xr[18 + a * 3] * y1z;
                const f16x4 rv = *(const f16x4*)&sh_R[w][n][128 + a * 8 + b0];
#pragma unroll
                for (int r = 0; r < 4; ++r) uuv[r] += xy * (float)rv[r];
            }
            f16x4 o;
#pragma unroll
            for (int r = 0; r < 4; ++r) o[r] = (_Float16)(y0 * ssv[r] + uuv[r]);
            *(f16x4*)&rec[b0] = o;
        } else {
            float suv[2] = {0.f, 0.f};
            float usv[2][3] = {{0.f, 0.f, 0.f}, {0.f, 0.f, 0.f}};
#pragma unroll
            for (int a = 0; a < 16; ++a) {
                const half2v rv = *(const half2v*)&sh_R[w][n][192 + a * 4 + b0];
                suv[0] += xr[a] * (float)rv[0];
                suv[1] += xr[a] * (float)rv[1];
            }
#pragma unroll
            for (int a = 0; a < 8; ++a) {
                const half2v rv = *(const half2v*)&sh_R[w][n][256 + a * 4 + b0];
#pragma unroll
                for (int bb = 0; bb < 2; ++bb) {
                    const float wv = (float)rv[bb];
                    usv[bb][0] += xr[16 + a * 3] * wv;
                    usv[bb][1] += xr[17 + a * 3] * wv;
                    usv[bb][2] += xr[18 + a * 3] * wv;
                }
            }
            float k1v[2][3];
#pragma unroll
            for (int bb = 0; bb < 2; ++bb) {
                k1v[bb][0] = suv[bb] * y1x + y0 * usv[bb][0];
                k1v[bb][1] = suv[bb] * y1y + y0 * usv[bb][1];
                k1v[bb][2] = suv[bb] * y1z + y0 * usv[bb][2];
            }
            const int base = 8 + b0 * 3;
            *(half2v*)&rec[base]     = half2v{(_Float16)k1v[0][0], (_Float16)k1v[0][1]};
            *(half2v*)&rec[base + 2] = half2v{(_Float16)k1v[0][2], (_Float16)k1v[1][0]};
            *(half2v*)&rec[base + 4] = half2v{(_Float16)k1v[1][1], (_Float16)k1v[1][2]};
        }
    }
}

// ---------- node gather: one wave per node, all lanes active, zero atomics ----------
__global__ __launch_bounds__(TPB) void node_gather(
    const int* __restrict__ offs,
    const float* __restrict__ evs, const _Float16* __restrict__ vsc,
    float* __restrict__ out)
{
    const int wv = threadIdx.x >> 6, lane = threadIdx.x & 63;
    const int j = blockIdx.x * 4 + wv;
    if (j >= NN) return;
    const int o0 = offs[j], cnt = offs[j + 1] - o0;

    float s = 0.f;
    for (int t = lane; t < cnt; t += 64) s += evs[o0 + t];
#pragma unroll
    for (int d = 1; d < 64; d <<= 1) s += __shfl_xor(s, d);
    const float invZ = (s > 0.f) ? (1.f / s) : 0.f;

    // 3 lane-groups x 20 components, stride-3 over the CSR run
    const int g = lane / 20, c = lane % 20;
    float acc = 0.f;
    if (g < 3) {
        for (int t = g; t < cnt; t += 3) {
            const float ev = evs[o0 + t];
            const float wgt = sqrtf(fmaxf(ev * invZ, 0.f));
            acc += wgt * (float)vsc[(size_t)(o0 + t) * 20 + c];
        }
    }
    const float a1 = __shfl(acc, lane + 20);
    const float a2 = __shfl(acc, lane + 40);
    if (lane < 20) out[(size_t)j * 20 + lane] = acc + a1 + a2;
}

extern "C" void kernel_launch(void* const* d_in, const int* in_sizes, int n_in,
                              void* d_out, int out_size, void* d_ws, size_t ws_size,
                              hipStream_t stream)
{
    const float* x     = (const float*)d_in[0];
    const int*   eidx  = (const int*)d_in[1];
    const float* eattr = (const float*)d_in[2];
    const float* emb   = (const float*)d_in[3];
    const float* elen  = (const float*)d_in[4];
    const float* wq0   = (const float*)d_in[5];
    const float* wq1   = (const float*)d_in[6];
    const float* wk1   = (const float*)d_in[7];
    const float* wk2   = (const float*)d_in[8];
    const float* wv1   = (const float*)d_in[9];
    const float* wv2   = (const float*)d_in[10];
    const float* wd0   = (const float*)d_in[11];
    const float* wd1   = (const float*)d_in[12];

    float* ws  = (float*)d_ws;
    float* out = (float*)d_out;

    half2v* w1pk = (half2v*)(ws + NW1K_OFF);
    half2v* w1pv = (half2v*)(ws + NW1V_OFF);
    _Float16* w2fk = (_Float16*)(ws + NW2K_OFF);
    _Float16* w2fv = (_Float16*)(ws + NW2V_OFF);
    int* cnt  = (int*)(ws + NCNT_OFF);
    int* offs = (int*)(ws + NOFF_OFF);
    int* c2   = (int*)(ws + NC2_OFF);
    int* pos  = (int*)(ws + NPOS_OFF);
    float* evs = ws + NEVS_OFF;
    _Float16* vsc = (_Float16*)(ws + NVSC_OFF);

    const int zblocks = (NN + TPB - 1) / TPB;          // 118
    prep_all<<<136 + zblocks, TPB, 0, stream>>>(
        x, wq0, wq1, wk1, wk2, wv1, wv2,
        w1pk, w1pv, w2fk, w2fv, ws + NQ_OFF, cnt, c2);

    hist_k<<<(NE + TPB - 1) / TPB, TPB, 0, stream>>>(eidx, cnt);
    scan_k<<<1, 1024, 0, stream>>>(cnt, offs);
    rank_k<<<(NE + TPB - 1) / TPB, TPB, 0, stream>>>(eidx, offs, c2, pos);

    edge_fused<<<NE / 32, ETPB, 0, stream>>>(
        x, eidx, eattr, emb, elen,
        w1pk, (const f16x8*)w2fk, w1pv, (const f16x8*)w2fv,
        wd0, wd1, ws + NQ_OFF, pos, evs, vsc);

    node_gather<<<(NN + 3) / 4, TPB, 0, stream>>>(offs, evs, vsc, out);
}